// Round 2
// baseline (2806.666 us; speedup 1.0000x reference)
//
#include <hip/hip_runtime.h>
#include <cmath>

constexpr int cB = 16, cL = 1024, cH = 256, cN = 64, cNB = 6, cNF = 4;
constexpr size_t SZ = (size_t)cB * cH * cL; // 4,194,304 elements per activation buffer

// ---------------------------------------------------------------- temb + tb
__global__ __launch_bounds__(256) void temb_kernel(
    const float* __restrict__ t, const float* __restrict__ Wt1, const float* __restrict__ bt1,
    const float* __restrict__ Wt2, const float* __restrict__ bt2,
    const float* __restrict__ Wt, const float* __restrict__ btb, float* __restrict__ tb) {
  __shared__ float e0[128], h1[256], h2[256];
  int b = blockIdx.x, tid = threadIdx.x;
  if (tid < 64) {
    float fr = expf((float)tid * (-logf(10000.0f) / 63.0f));
    float ang = t[b] * fr;
    e0[tid] = sinf(ang);
    e0[tid + 64] = cosf(ang);
  }
  __syncthreads();
  float a = bt1[tid];
  for (int k = 0; k < 128; ++k) a = fmaf(e0[k], Wt1[k * cH + tid], a);
  h1[tid] = a / (1.0f + expf(-a));   // silu
  __syncthreads();
  a = bt2[tid];
  for (int k = 0; k < 256; ++k) a = fmaf(h1[k], Wt2[k * cH + tid], a);
  h2[tid] = a / (1.0f + expf(-a));
  __syncthreads();
  for (int i = 0; i < cNB; ++i) {
    float acc = btb[i * cH + tid];
    const float* w = Wt + (size_t)i * cH * cH;
    for (int k = 0; k < 256; ++k) acc = fmaf(h2[k], w[k * cH + tid], acc);
    tb[((size_t)i * cB + b) * cH + tid] = acc;
  }
}

// ---------------------------------------------------------------- x init + skip=0
__global__ __launch_bounds__(256) void init_kernel(const float* __restrict__ inp,
    const float* __restrict__ Win, const float* __restrict__ bin,
    float* __restrict__ x, float* __restrict__ skip) {
  int idx = blockIdx.x * 256 + threadIdx.x;
  int l = idx & (cL - 1);
  int h = (idx >> 10) & (cH - 1);
  int b = idx >> 18;
  float v = fmaf(inp[b * cL + l], Win[h], bin[h]);
  x[idx] = v > 0.0f ? v : 0.0f;
  skip[idx] = 0.0f;
}

// ---------------------------------------------------------------- z = LN_H(x + tb)  (u recomputed, not stored)
__global__ __launch_bounds__(256) void pre_ln_kernel(const float* __restrict__ x,
    const float* __restrict__ tb_all, const float* __restrict__ ln_g, const float* __restrict__ ln_b,
    float* __restrict__ z, int blk) {
  __shared__ float red[8][64];
  __shared__ float mur[64], rsr[64];
  int b = blockIdx.x >> 4;
  int l0 = (blockIdx.x & 15) << 6;
  int lq = threadIdx.x & 63, hq = threadIdx.x >> 6; // 4 h-groups of 64
  int l = l0 + lq;
  const float* tb = tb_all + ((size_t)blk * cB + b) * cH;
  size_t base = ((size_t)b * cH + hq * 64) * cL + l;
  float s = 0.0f, s2 = 0.0f;
  for (int hh = 0; hh < 64; ++hh) {
    float v = x[base + (size_t)hh * cL] + tb[hq * 64 + hh];
    s += v;
    s2 = fmaf(v, v, s2);
  }
  red[hq][lq] = s;
  red[4 + hq][lq] = s2;
  __syncthreads();
  if (hq == 0) {
    float st = red[0][lq] + red[1][lq] + red[2][lq] + red[3][lq];
    float s2t = red[4][lq] + red[5][lq] + red[6][lq] + red[7][lq];
    float mu = st * (1.0f / cH);
    float var = s2t * (1.0f / cH) - mu * mu;
    mur[lq] = mu;
    rsr[lq] = rsqrtf(var + 1e-5f);
  }
  __syncthreads();
  float mu = mur[lq], r = rsr[lq];
  const float* g = ln_g + blk * cH;
  const float* be = ln_b + blk * cH;
  for (int hh = 0; hh < 64; ++hh) {
    int h = hq * 64 + hh;
    float v = (x[base + (size_t)hh * cL] + tb[h] - mu) * r;
    z[base + (size_t)hh * cL] = fmaf(v, g[h], be[h]);
  }
}

// ---------------------------------------------------------------- bidirectional SSM scan
// wave: 8 lanes per channel (8 states each), 8 channels per wave. dir = blockIdx.y.
__global__ __launch_bounds__(256) void scan_kernel(
    const float* __restrict__ zb, const float* __restrict__ log_dt,
    const float* __restrict__ A_re, const float* __restrict__ A_im,
    const float* __restrict__ C_re, const float* __restrict__ C_im,
    float* __restrict__ yf, float* __restrict__ ybk, int blk) {
  int dir = blockIdx.y;
  int b = blockIdx.x >> 3;
  int h0 = (blockIdx.x & 7) << 5;
  int tid = threadIdx.x;
  int wv = tid >> 6, lane = tid & 63;
  int hs = lane >> 3, j = lane & 7;
  int h = h0 + wv * 8 + hs;
  float dt = expf(log_dt[blk * cH + h]);
  const float* Ar = A_re + ((size_t)blk * cH + h) * cN;
  const float* Ai = A_im + ((size_t)blk * cH + h) * cN;
  const float* Cr = C_re + (((size_t)blk * 2 + dir) * cH + h) * cN;
  const float* Ci = C_im + (((size_t)blk * 2 + dir) * cH + h) * cN;
  float wr[8], wi[8], br[8], bi[8], sr[8], si[8];
#pragma unroll
  for (int k = 0; k < 8; ++k) {
    int n = j * 8 + k;
    float are = Ar[n], aim = Ai[n];
    float e = expf(-dt * are);
    float sn, cs;
    sincosf(dt * aim, &sn, &cs);
    float w_r = e * cs, w_i = e * sn;
    // Bt = C * (w-1)/A, A = -are + i*aim ; fold factor 2 (2*Re) into Bt
    float inv = 1.0f / (are * are + aim * aim);
    float xr = w_r - 1.0f, xi = w_i;
    float tr = (xi * aim - xr * are) * inv;
    float ti = (-xr * aim - xi * are) * inv;
    float cr = Cr[n], ci = Ci[n];
    br[k] = 2.0f * (cr * tr - ci * ti);
    bi[k] = 2.0f * (cr * ti + ci * tr);
    wr[k] = w_r; wi[k] = w_i;
    sr[k] = 0.0f; si[k] = 0.0f;
  }
  const float* zr = zb + ((size_t)b * cH + h) * cL;
  if (dir == 0) {
    float* yr = yf + ((size_t)b * cH + h) * cL;
    for (int l = 0; l < cL; ++l) {
      float zv = zr[l];
      float p = 0.0f;
#pragma unroll
      for (int k = 0; k < 8; ++k) {
        float nr = fmaf(wr[k], sr[k], zv);
        nr = fmaf(-wi[k], si[k], nr);
        float ni = wr[k] * si[k];
        ni = fmaf(wi[k], sr[k], ni);
        sr[k] = nr; si[k] = ni;
        p = fmaf(br[k], nr, p);
        p = fmaf(-bi[k], ni, p);
      }
      p += __shfl_xor(p, 1);
      p += __shfl_xor(p, 2);
      p += __shfl_xor(p, 4);
      if (j == 0) yr[l] = p;
    }
  } else {
    // y_b[l] = 2Re(bt1 . r[l]),  r[l] = z[l+1] + w*r[l+1], r[L-1]=0
    float* yr = ybk + ((size_t)b * cH + h) * cL;
    for (int l = cL - 1; l >= 0; --l) {
      float p = 0.0f;
#pragma unroll
      for (int k = 0; k < 8; ++k) {
        p = fmaf(br[k], sr[k], p);
        p = fmaf(-bi[k], si[k], p);
      }
      p += __shfl_xor(p, 1);
      p += __shfl_xor(p, 2);
      p += __shfl_xor(p, 4);
      if (j == 0) yr[l] = p;
      float zv = zr[l];
#pragma unroll
      for (int k = 0; k < 8; ++k) {
        float nr = fmaf(wr[k], sr[k], zv);
        nr = fmaf(-wi[k], si[k], nr);
        float ni = wr[k] * si[k];
        ni = fmaf(wi[k], sr[k], ni);
        sr[k] = nr; si[k] = ni;
      }
    }
  }
}

// ---------------------------------------------------------------- y = gelu(yf + yb + z*D)
__global__ __launch_bounds__(256) void gelu_kernel(const float* __restrict__ y2,
    const float* __restrict__ zz, const float* __restrict__ Dp, float* __restrict__ y1io, int blk) {
  int idx = blockIdx.x * 256 + threadIdx.x;
  int h = (idx >> 10) & (cH - 1);
  float v = y1io[idx] + y2[idx] + zz[idx] * Dp[blk * cH + h];
  y1io[idx] = 0.5f * v * (1.0f + erff(v * 0.70710678118654752f));
}

// ================================================================ GEMM core: 128(l) x 64(o) tile,
// 256 threads, 8x4 micro-tile. acc[o_i 0..3][l_i 0..7].
#define GEMM_CORE(WPTR)                                                          \
  int l0 = blockIdx.x * 128, o0 = blockIdx.y * 64, b = blockIdx.z;               \
  int tid = threadIdx.x;                                                         \
  int tx = tid & 15, ty = tid >> 4;                                              \
  const float* Gb = G + (size_t)b * cH * cL;                                     \
  float acc[4][8] = {};                                                          \
  {                                                                              \
    int ar = tid >> 6, ac = tid & 63;                                            \
    int brr = tid >> 7, bc = tid & 127;                                          \
    for (int kk = 0; kk < cH; kk += 16) {                                        \
      _Pragma("unroll")                                                          \
      for (int rr = 0; rr < 4; ++rr)                                             \
        As[ar + rr * 4][ac] = (WPTR)[(size_t)(kk + ar + rr * 4) * cH + o0 + ac]; \
      _Pragma("unroll")                                                          \
      for (int rr = 0; rr < 8; ++rr)                                             \
        Bs[brr + rr * 2][bc] = Gb[(size_t)(kk + brr + rr * 2) * cL + l0 + bc];   \
      __syncthreads();                                                           \
      _Pragma("unroll")                                                          \
      for (int k = 0; k < 16; ++k) {                                             \
        const float4 av = *(const float4*)&As[k][ty << 2];                       \
        const float4 b0 = *(const float4*)&Bs[k][tx << 3];                       \
        const float4 b1 = *(const float4*)&Bs[k][(tx << 3) + 4];                 \
        FMA8(0, av.x) FMA8(1, av.y) FMA8(2, av.z) FMA8(3, av.w)                  \
      }                                                                          \
      __syncthreads();                                                           \
    }                                                                            \
  }

#define FMA8(oi, aw)                                     \
  acc[oi][0] = fmaf(aw, b0.x, acc[oi][0]);               \
  acc[oi][1] = fmaf(aw, b0.y, acc[oi][1]);               \
  acc[oi][2] = fmaf(aw, b0.z, acc[oi][2]);               \
  acc[oi][3] = fmaf(aw, b0.w, acc[oi][3]);               \
  acc[oi][4] = fmaf(aw, b1.x, acc[oi][4]);               \
  acc[oi][5] = fmaf(aw, b1.y, acc[oi][5]);               \
  acc[oi][6] = fmaf(aw, b1.z, acc[oi][6]);               \
  acc[oi][7] = fmaf(aw, b1.w, acc[oi][7]);

// ---------------------------------------------------------------- s4-out GEMM fused with gated activation:
// g = act( (y @ Wo + bo) + (x + tb) + feat@Wf + bf ),  act(v)=tanh(v)*sigmoid(v)
__global__ __launch_bounds__(256) void gemm_act_kernel(const float* __restrict__ W,
    const float* __restrict__ bo, const float* __restrict__ G,
    const float* __restrict__ x, const float* __restrict__ tb_all,
    const float* __restrict__ features, const float* __restrict__ Wf,
    const float* __restrict__ bfb, float* __restrict__ C, int blk) {
  __shared__ float As[16][64];
  __shared__ float Bs[16][128];
  GEMM_CORE(W)
  int lbase = l0 + (tx << 3);
  float4 fv[8];
#pragma unroll
  for (int li = 0; li < 8; ++li)
    fv[li] = *(const float4*)&features[((size_t)b * cL + lbase + li) * cNF];
  const float* Wfi = Wf + (size_t)blk * cNF * cH;
  const float* tb = tb_all + ((size_t)blk * cB + b) * cH;
#pragma unroll
  for (int oi = 0; oi < 4; ++oi) {
    int oo = o0 + (ty << 2) + oi;
    float wf0 = Wfi[oo], wf1 = Wfi[cH + oo], wf2 = Wfi[2 * cH + oo], wf3 = Wfi[3 * cH + oo];
    float bb = bo[oo] + bfb[blk * cH + oo] + tb[oo];
    size_t row = ((size_t)b * cH + oo) * cL + lbase;
    const float4 x0 = *(const float4*)&x[row];
    const float4 x1 = *(const float4*)&x[row + 4];
    float xv[8] = {x0.x, x0.y, x0.z, x0.w, x1.x, x1.y, x1.z, x1.w};
    float out[8];
#pragma unroll
    for (int li = 0; li < 8; ++li) {
      float v = acc[oi][li] + bb + xv[li];
      v = fmaf(fv[li].x, wf0, v);
      v = fmaf(fv[li].y, wf1, v);
      v = fmaf(fv[li].z, wf2, v);
      v = fmaf(fv[li].w, wf3, v);
      float tv = tanhf(v);
      float sv = 1.0f / (1.0f + expf(-v));
      out[li] = tv * sv;
    }
    *(float4*)&C[row] = make_float4(out[0], out[1], out[2], out[3]);
    *(float4*)&C[row + 4] = make_float4(out[4], out[5], out[6], out[7]);
  }
}

// ---------------------------------------------------------------- dual GEMM: x += g@W1 + b1 ; skip += g@W2 + b2
__global__ __launch_bounds__(256) void gemm_dual_kernel(const float* __restrict__ W1,
    const float* __restrict__ b1, const float* __restrict__ W2, const float* __restrict__ b2,
    const float* __restrict__ G, float* __restrict__ xio, float* __restrict__ skio) {
  __shared__ float As[16][64];
  __shared__ float As2[16][64];
  __shared__ float Bs[16][128];
  int l0 = blockIdx.x * 128, o0 = blockIdx.y * 64, b = blockIdx.z;
  int tid = threadIdx.x;
  int tx = tid & 15, ty = tid >> 4;
  const float* Gb = G + (size_t)b * cH * cL;
  float acc[4][8] = {};
  float acc2[4][8] = {};
  {
    int ar = tid >> 6, ac = tid & 63;
    int brr = tid >> 7, bc = tid & 127;
    for (int kk = 0; kk < cH; kk += 16) {
#pragma unroll
      for (int rr = 0; rr < 4; ++rr) {
        As[ar + rr * 4][ac] = W1[(size_t)(kk + ar + rr * 4) * cH + o0 + ac];
        As2[ar + rr * 4][ac] = W2[(size_t)(kk + ar + rr * 4) * cH + o0 + ac];
      }
#pragma unroll
      for (int rr = 0; rr < 8; ++rr)
        Bs[brr + rr * 2][bc] = Gb[(size_t)(kk + brr + rr * 2) * cL + l0 + bc];
      __syncthreads();
#pragma unroll
      for (int k = 0; k < 16; ++k) {
        const float4 b0 = *(const float4*)&Bs[k][tx << 3];
        const float4 b1v = *(const float4*)&Bs[k][(tx << 3) + 4];
        {
          const float4 av = *(const float4*)&As[k][ty << 2];
#define FMA8D(AC, oi, aw)                          \
  AC[oi][0] = fmaf(aw, b0.x, AC[oi][0]);           \
  AC[oi][1] = fmaf(aw, b0.y, AC[oi][1]);           \
  AC[oi][2] = fmaf(aw, b0.z, AC[oi][2]);           \
  AC[oi][3] = fmaf(aw, b0.w, AC[oi][3]);           \
  AC[oi][4] = fmaf(aw, b1v.x, AC[oi][4]);          \
  AC[oi][5] = fmaf(aw, b1v.y, AC[oi][5]);          \
  AC[oi][6] = fmaf(aw, b1v.z, AC[oi][6]);          \
  AC[oi][7] = fmaf(aw, b1v.w, AC[oi][7]);
          FMA8D(acc, 0, av.x) FMA8D(acc, 1, av.y) FMA8D(acc, 2, av.z) FMA8D(acc, 3, av.w)
        }
        {
          const float4 av = *(const float4*)&As2[k][ty << 2];
          FMA8D(acc2, 0, av.x) FMA8D(acc2, 1, av.y) FMA8D(acc2, 2, av.z) FMA8D(acc2, 3, av.w)
        }
      }
      __syncthreads();
    }
  }
  int lbase = l0 + (tx << 3);
#pragma unroll
  for (int oi = 0; oi < 4; ++oi) {
    int oo = o0 + (ty << 2) + oi;
    float bb1 = b1[oo], bb2 = b2[oo];
    size_t row = ((size_t)b * cH + oo) * cL + lbase;
    float4 xv0 = *(const float4*)&xio[row];
    float4 xv1 = *(const float4*)&xio[row + 4];
    float4 sv0 = *(const float4*)&skio[row];
    float4 sv1 = *(const float4*)&skio[row + 4];
    xv0.x += acc[oi][0] + bb1; xv0.y += acc[oi][1] + bb1;
    xv0.z += acc[oi][2] + bb1; xv0.w += acc[oi][3] + bb1;
    xv1.x += acc[oi][4] + bb1; xv1.y += acc[oi][5] + bb1;
    xv1.z += acc[oi][6] + bb1; xv1.w += acc[oi][7] + bb1;
    sv0.x += acc2[oi][0] + bb2; sv0.y += acc2[oi][1] + bb2;
    sv0.z += acc2[oi][2] + bb2; sv0.w += acc2[oi][3] + bb2;
    sv1.x += acc2[oi][4] + bb2; sv1.y += acc2[oi][5] + bb2;
    sv1.z += acc2[oi][6] + bb2; sv1.w += acc2[oi][7] + bb2;
    *(float4*)&xio[row] = xv0;
    *(float4*)&xio[row + 4] = xv1;
    *(float4*)&skio[row] = sv0;
    *(float4*)&skio[row + 4] = sv1;
  }
}

// ---------------------------------------------------------------- head GEMM: C = relu(skip^T Wh1 + bh1), (B,256,L)
__global__ __launch_bounds__(256) void gemm_relu_kernel(const float* __restrict__ W,
    const float* __restrict__ bias, const float* __restrict__ G, float* __restrict__ C) {
  __shared__ float As[16][64];
  __shared__ float Bs[16][128];
  GEMM_CORE(W)
  int lbase = l0 + (tx << 3);
#pragma unroll
  for (int oi = 0; oi < 4; ++oi) {
    int oo = o0 + (ty << 2) + oi;
    float bb = bias[oo];
    size_t row = ((size_t)b * cH + oo) * cL + lbase;
    float4 v0, v1;
    v0.x = fmaxf(acc[oi][0] + bb, 0.0f); v0.y = fmaxf(acc[oi][1] + bb, 0.0f);
    v0.z = fmaxf(acc[oi][2] + bb, 0.0f); v0.w = fmaxf(acc[oi][3] + bb, 0.0f);
    v1.x = fmaxf(acc[oi][4] + bb, 0.0f); v1.y = fmaxf(acc[oi][5] + bb, 0.0f);
    v1.z = fmaxf(acc[oi][6] + bb, 0.0f); v1.w = fmaxf(acc[oi][7] + bb, 0.0f);
    *(float4*)&C[row] = v0;
    *(float4*)&C[row + 4] = v1;
  }
}

// ---------------------------------------------------------------- out = h @ Wh2 + bh2 + input
__global__ __launch_bounds__(256) void head_kernel(const float* __restrict__ hb,
    const float* __restrict__ Wh2, const float* __restrict__ bh2,
    const float* __restrict__ inp, float* __restrict__ out) {
  int idx = blockIdx.x * 256 + threadIdx.x; // B*L
  int b = idx >> 10, l = idx & (cL - 1);
  float acc = bh2[0] + inp[idx];
  const float* hr = hb + (size_t)b * cH * cL + l;
  for (int o = 0; o < cH; ++o) acc = fmaf(hr[(size_t)o * cL], Wh2[o], acc);
  out[idx] = acc;
}

// ----------------------------------------------------------------
extern "C" void kernel_launch(void* const* d_in, const int* in_sizes, int n_in,
                              void* d_out, int out_size, void* d_ws, size_t ws_size,
                              hipStream_t stream) {
  const float* input = (const float*)d_in[0];
  const float* t     = (const float*)d_in[1];
  const float* feats = (const float*)d_in[2];
  const float* W_in  = (const float*)d_in[3];
  const float* b_in  = (const float*)d_in[4];
  const float* W_t1  = (const float*)d_in[5];
  const float* b_t1  = (const float*)d_in[6];
  const float* W_t2  = (const float*)d_in[7];
  const float* b_t2  = (const float*)d_in[8];
  const float* Wh1   = (const float*)d_in[9];
  const float* bh1   = (const float*)d_in[10];
  const float* Wh2   = (const float*)d_in[11];
  const float* bh2   = (const float*)d_in[12];
  const float* ln_g  = (const float*)d_in[13];
  const float* ln_b  = (const float*)d_in[14];
  const float* logdt = (const float*)d_in[15];
  const float* A_re  = (const float*)d_in[16];
  const float* A_im  = (const float*)d_in[17];
  const float* C_re  = (const float*)d_in[18];
  const float* C_im  = (const float*)d_in[19];
  const float* Dp    = (const float*)d_in[20];
  const float* Wo_s4 = (const float*)d_in[21];
  const float* bo_s4 = (const float*)d_in[22];
  const float* Wt    = (const float*)d_in[23];
  const float* bt_   = (const float*)d_in[24];
  const float* W1    = (const float*)d_in[25];
  const float* b1    = (const float*)d_in[26];
  const float* W2    = (const float*)d_in[27];
  const float* b2    = (const float*)d_in[28];
  const float* Wf    = (const float*)d_in[29];
  const float* bf_   = (const float*)d_in[30];

  float* ws = (float*)d_ws;
  float* xb   = ws;            // x (B,H,L)
  float* skb  = ws + SZ;       // skip
  float* zbuf = ws + 2 * SZ;   // LN out -> later g buffer
  float* yb   = ws + 3 * SZ;   // fwd conv partial -> gelu out -> head relu out
  float* y2b  = ws + 4 * SZ;   // bwd conv partial
  float* tbb  = ws + 5 * SZ;   // (NB,B,H)

  dim3 ggrid(cL / 128, cH / 64, cB);

  temb_kernel<<<cB, 256, 0, stream>>>(t, W_t1, b_t1, W_t2, b_t2, Wt, bt_, tbb);
  init_kernel<<<(int)(SZ / 256), 256, 0, stream>>>(input, W_in, b_in, xb, skb);

  for (int i = 0; i < cNB; ++i) {
    pre_ln_kernel<<<cB * (cL / 64), 256, 0, stream>>>(xb, tbb, ln_g, ln_b, zbuf, i);
    scan_kernel<<<dim3(cB * (cH / 32), 2), 256, 0, stream>>>(zbuf, logdt, A_re, A_im, C_re, C_im, yb, y2b, i);
    gelu_kernel<<<(int)(SZ / 256), 256, 0, stream>>>(y2b, zbuf, Dp, yb, i);
    gemm_act_kernel<<<ggrid, 256, 0, stream>>>(
        Wo_s4 + (size_t)i * cH * cH, bo_s4 + i * cH, yb, xb, tbb, feats, Wf, bf_, zbuf, i);
    gemm_dual_kernel<<<ggrid, 256, 0, stream>>>(
        W1 + (size_t)i * cH * cH, b1 + i * cH, W2 + (size_t)i * cH * cH, b2 + i * cH,
        zbuf, xb, skb);
  }

  // head: h = relu(skip^T Wh1 + bh1) stored (B,256,L) in yb, then scalar head
  gemm_relu_kernel<<<ggrid, 256, 0, stream>>>(Wh1, bh1, skb, yb);
  head_kernel<<<(cB * cL) / 256, 256, 0, stream>>>(yb, Wh2, bh2, input, (float*)d_out);
}

// Round 6
// 1941.866 us; speedup vs baseline: 1.4453x; 1.4453x over previous
//
#include <hip/hip_runtime.h>
#include <cmath>

constexpr int cB = 16, cL = 1024, cH = 256, cN = 64, cNB = 6, cNF = 4;
constexpr int cC = 8, cLc = cL / cC;           // chunked scan: 8 chunks of 128
constexpr size_t SZ = (size_t)cB * cH * cL;    // 4,194,304 elements per activation buffer

// ---------------------------------------------------------------- temb + tb
__global__ __launch_bounds__(256) void temb_kernel(
    const float* __restrict__ t, const float* __restrict__ Wt1, const float* __restrict__ bt1,
    const float* __restrict__ Wt2, const float* __restrict__ bt2,
    const float* __restrict__ Wt, const float* __restrict__ btb, float* __restrict__ tb) {
  __shared__ float e0[128], h1[256], h2[256];
  int b = blockIdx.x, tid = threadIdx.x;
  if (tid < 64) {
    float fr = expf((float)tid * (-logf(10000.0f) / 63.0f));
    float ang = t[b] * fr;
    e0[tid] = sinf(ang);
    e0[tid + 64] = cosf(ang);
  }
  __syncthreads();
  float a = bt1[tid];
  for (int k = 0; k < 128; ++k) a = fmaf(e0[k], Wt1[k * cH + tid], a);
  h1[tid] = a / (1.0f + expf(-a));   // silu
  __syncthreads();
  a = bt2[tid];
  for (int k = 0; k < 256; ++k) a = fmaf(h1[k], Wt2[k * cH + tid], a);
  h2[tid] = a / (1.0f + expf(-a));
  __syncthreads();
  for (int i = 0; i < cNB; ++i) {
    float acc = btb[i * cH + tid];
    const float* w = Wt + (size_t)i * cH * cH;
    for (int k = 0; k < 256; ++k) acc = fmaf(h2[k], w[k * cH + tid], acc);
    tb[((size_t)i * cB + b) * cH + tid] = acc;
  }
}

// ---------------------------------------------------------------- x init + skip=0
__global__ __launch_bounds__(256) void init_kernel(const float* __restrict__ inp,
    const float* __restrict__ Win, const float* __restrict__ bin,
    float* __restrict__ x, float* __restrict__ skip) {
  int idx = blockIdx.x * 256 + threadIdx.x;
  int l = idx & (cL - 1);
  int h = (idx >> 10) & (cH - 1);
  int b = idx >> 18;
  float v = fmaf(inp[b * cL + l], Win[h], bin[h]);
  x[idx] = v > 0.0f ? v : 0.0f;
  skip[idx] = 0.0f;
}

// ---------------------------------------------------------------- z = LN_H(x + tb)  (u recomputed, not stored)
__global__ __launch_bounds__(256) void pre_ln_kernel(const float* __restrict__ x,
    const float* __restrict__ tb_all, const float* __restrict__ ln_g, const float* __restrict__ ln_b,
    float* __restrict__ z, int blk) {
  __shared__ float red[8][64];
  __shared__ float mur[64], rsr[64];
  int b = blockIdx.x >> 4;
  int l0 = (blockIdx.x & 15) << 6;
  int lq = threadIdx.x & 63, hq = threadIdx.x >> 6; // 4 h-groups of 64
  int l = l0 + lq;
  const float* tb = tb_all + ((size_t)blk * cB + b) * cH;
  size_t base = ((size_t)b * cH + hq * 64) * cL + l;
  float s = 0.0f, s2 = 0.0f;
  for (int hh = 0; hh < 64; ++hh) {
    float v = x[base + (size_t)hh * cL] + tb[hq * 64 + hh];
    s += v;
    s2 = fmaf(v, v, s2);
  }
  red[hq][lq] = s;
  red[4 + hq][lq] = s2;
  __syncthreads();
  if (hq == 0) {
    float st = red[0][lq] + red[1][lq] + red[2][lq] + red[3][lq];
    float s2t = red[4][lq] + red[5][lq] + red[6][lq] + red[7][lq];
    float mu = st * (1.0f / cH);
    float var = s2t * (1.0f / cH) - mu * mu;
    mur[lq] = mu;
    rsr[lq] = rsqrtf(var + 1e-5f);
  }
  __syncthreads();
  float mu = mur[lq], r = rsr[lq];
  const float* g = ln_g + blk * cH;
  const float* be = ln_b + blk * cH;
  for (int hh = 0; hh < 64; ++hh) {
    int h = hq * 64 + hh;
    float v = (x[base + (size_t)hh * cL] + tb[h] - mu) * r;
    z[base + (size_t)hh * cL] = fmaf(v, g[h], be[h]);
  }
}

// ---------------------------------------------------------------- S4 per-block params:
// P[(dir*cH+h)*cN+n] = (wr, wi, br, bi); PW[h*cN+n] = w^Lc  (dir-independent)
__global__ __launch_bounds__(256) void s4param_kernel(
    const float* __restrict__ logdt, const float* __restrict__ Are, const float* __restrict__ Aim,
    const float* __restrict__ Cre, const float* __restrict__ Cim,
    float4* __restrict__ P, float2* __restrict__ PW, int blk) {
  int idx = blockIdx.x * 256 + threadIdx.x;      // (dir*cH+h)*cN+n, 32768 total
  int n = idx & (cN - 1);
  int h = (idx >> 6) & (cH - 1);
  int dir = idx >> 14;
  float dt = expf(logdt[blk * cH + h]);
  float are = Are[((size_t)blk * cH + h) * cN + n];
  float aim = Aim[((size_t)blk * cH + h) * cN + n];
  float e = expf(-dt * are);
  float sn, cs;
  sincosf(dt * aim, &sn, &cs);
  float wr = e * cs, wi = e * sn;
  float inv = 1.0f / (are * are + aim * aim);
  float xr = wr - 1.0f, xi = wi;
  float tr = (xi * aim - xr * are) * inv;
  float ti = (-xr * aim - xi * are) * inv;
  float cr = Cre[(((size_t)blk * 2 + dir) * cH + h) * cN + n];
  float ci = Cim[(((size_t)blk * 2 + dir) * cH + h) * cN + n];
  float br = 2.0f * (cr * tr - ci * ti);
  float bi = 2.0f * (cr * ti + ci * tr);
  P[idx] = make_float4(wr, wi, br, bi);
  if (dir == 0) {
    float rr = wr, ri = wi;                      // w^128 by 7 squarings
#pragma unroll
    for (int q = 0; q < 7; ++q) {
      float nr = rr * rr - ri * ri;
      ri = 2.0f * rr * ri;
      rr = nr;
    }
    PW[h * cN + n] = make_float2(rr, ri);
  }
}

// ---------------------------------------------------------------- scan phase A1: per-chunk end states
// grid (cC, cB*cH/32, 2). wave: 8 lanes/channel x 8 states/lane, 8 channels/wave.
__global__ __launch_bounds__(256) void scanA1_kernel(const float* __restrict__ zb,
    const float4* __restrict__ P, float2* __restrict__ E) {
  int c = blockIdx.x, bh = blockIdx.y, dir = blockIdx.z;
  int b = bh >> 3, h0 = (bh & 7) << 5;
  int tid = threadIdx.x, wv = tid >> 6, lane = tid & 63;
  int hs = lane >> 3, j = lane & 7;
  int h = h0 + wv * 8 + hs;
  float wr[8], wi[8], sr[8], si[8];
  const float4* Ph = P + ((size_t)dir * cH + h) * cN + j * 8;
#pragma unroll
  for (int k = 0; k < 8; ++k) {
    float4 p4 = Ph[k];
    wr[k] = p4.x; wi[k] = p4.y;
    sr[k] = 0.0f; si[k] = 0.0f;
  }
  const float* zr = zb + ((size_t)b * cH + h) * cL;
  int c0 = c * cLc;
  if (dir == 0) {
    for (int m = 0; m < cLc / 4; ++m) {
      float4 z4 = *(const float4*)&zr[c0 + (m << 2)];
#pragma unroll
      for (int q = 0; q < 4; ++q) {
        float zv = q == 0 ? z4.x : q == 1 ? z4.y : q == 2 ? z4.z : z4.w;
#pragma unroll
        for (int k = 0; k < 8; ++k) {
          float nr = fmaf(wr[k], sr[k], zv);
          nr = fmaf(-wi[k], si[k], nr);
          float ni = wr[k] * si[k];
          ni = fmaf(wi[k], sr[k], ni);
          sr[k] = nr; si[k] = ni;
        }
      }
    }
  } else {
    for (int m = cLc / 4 - 1; m >= 0; --m) {
      float4 z4 = *(const float4*)&zr[c0 + (m << 2)];
#pragma unroll
      for (int q = 3; q >= 0; --q) {
        float zv = q == 0 ? z4.x : q == 1 ? z4.y : q == 2 ? z4.z : z4.w;
#pragma unroll
        for (int k = 0; k < 8; ++k) {
          float nr = fmaf(wr[k], sr[k], zv);
          nr = fmaf(-wi[k], si[k], nr);
          float ni = wr[k] * si[k];
          ni = fmaf(wi[k], sr[k], ni);
          sr[k] = nr; si[k] = ni;
        }
      }
    }
  }
  float2* Eo = E + ((((size_t)dir * cC + c) * cB + b) * cH + h) * cN + j * 8;
#pragma unroll
  for (int k = 0; k < 8; ++k) Eo[k] = make_float2(sr[k], si[k]);
}

// ---------------------------------------------------------------- scan phase A2: carry fold + full scan with output
__global__ __launch_bounds__(256) void scanA2_kernel(const float* __restrict__ zb,
    const float4* __restrict__ P, const float2* __restrict__ PW, const float2* __restrict__ E,
    float* __restrict__ yf, float* __restrict__ ybk) {
  int c = blockIdx.x, bh = blockIdx.y, dir = blockIdx.z;
  int b = bh >> 3, h0 = (bh & 7) << 5;
  int tid = threadIdx.x, wv = tid >> 6, lane = tid & 63;
  int hs = lane >> 3, j = lane & 7;
  int h = h0 + wv * 8 + hs;
  float sr[8] = {}, si[8] = {};
  // ---- fold carry from other chunks' end states
  {
    float qr[8], qi[8];
    const float2* PWh = PW + (size_t)h * cN + j * 8;
#pragma unroll
    for (int k = 0; k < 8; ++k) {
      float2 q2 = PWh[k];
      qr[k] = q2.x; qi[k] = q2.y;
    }
    const size_t cstride = (size_t)cB * cH * cN;   // float2 units per chunk slot
    const float2* Eb = E + (((size_t)dir * cC * cB + b) * cH + h) * cN + j * 8;
    if (dir == 0) {
      for (int cc = 0; cc < c; ++cc) {
        const float2* Ec = Eb + cc * cstride;
#pragma unroll
        for (int k = 0; k < 8; ++k) {
          float2 e2 = Ec[k];
          float t_r = fmaf(qr[k], sr[k], e2.x);
          t_r = fmaf(-qi[k], si[k], t_r);
          float t_i = fmaf(qr[k], si[k], e2.y);
          t_i = fmaf(qi[k], sr[k], t_i);
          sr[k] = t_r; si[k] = t_i;
        }
      }
    } else {
      for (int cc = cC - 1; cc > c; --cc) {
        const float2* Ec = Eb + cc * cstride;
#pragma unroll
        for (int k = 0; k < 8; ++k) {
          float2 e2 = Ec[k];
          float t_r = fmaf(qr[k], sr[k], e2.x);
          t_r = fmaf(-qi[k], si[k], t_r);
          float t_i = fmaf(qr[k], si[k], e2.y);
          t_i = fmaf(qi[k], sr[k], t_i);
          sr[k] = t_r; si[k] = t_i;
        }
      }
    }
  }
  // ---- load w, bt
  float wr[8], wi[8], br[8], bi[8];
  const float4* Ph = P + ((size_t)dir * cH + h) * cN + j * 8;
#pragma unroll
  for (int k = 0; k < 8; ++k) {
    float4 p4 = Ph[k];
    wr[k] = p4.x; wi[k] = p4.y; br[k] = p4.z; bi[k] = p4.w;
  }
  const float* zr = zb + ((size_t)b * cH + h) * cL;
  int c0 = c * cLc;
  if (dir == 0) {
    float* yr = yf + ((size_t)b * cH + h) * cL;
    for (int m = 0; m < cLc / 4; ++m) {
      float4 z4 = *(const float4*)&zr[c0 + (m << 2)];
#pragma unroll
      for (int q = 0; q < 4; ++q) {
        float zv = q == 0 ? z4.x : q == 1 ? z4.y : q == 2 ? z4.z : z4.w;
        float p = 0.0f;
#pragma unroll
        for (int k = 0; k < 8; ++k) {
          float nr = fmaf(wr[k], sr[k], zv);
          nr = fmaf(-wi[k], si[k], nr);
          float ni = wr[k] * si[k];
          ni = fmaf(wi[k], sr[k], ni);
          sr[k] = nr; si[k] = ni;
          p = fmaf(br[k], nr, p);
          p = fmaf(-bi[k], ni, p);
        }
        p += __shfl_xor(p, 1);
        p += __shfl_xor(p, 2);
        p += __shfl_xor(p, 4);
        if (j == 0) yr[c0 + (m << 2) + q] = p;
      }
    }
  } else {
    float* yr = ybk + ((size_t)b * cH + h) * cL;
    for (int m = cLc / 4 - 1; m >= 0; --m) {
      float4 z4 = *(const float4*)&zr[c0 + (m << 2)];
#pragma unroll
      for (int q = 3; q >= 0; --q) {
        float zv = q == 0 ? z4.x : q == 1 ? z4.y : q == 2 ? z4.z : z4.w;
        float p = 0.0f;
#pragma unroll
        for (int k = 0; k < 8; ++k) {
          p = fmaf(br[k], sr[k], p);
          p = fmaf(-bi[k], si[k], p);
        }
        p += __shfl_xor(p, 1);
        p += __shfl_xor(p, 2);
        p += __shfl_xor(p, 4);
        if (j == 0) yr[c0 + (m << 2) + q] = p;
#pragma unroll
        for (int k = 0; k < 8; ++k) {
          float nr = fmaf(wr[k], sr[k], zv);
          nr = fmaf(-wi[k], si[k], nr);
          float ni = wr[k] * si[k];
          ni = fmaf(wi[k], sr[k], ni);
          sr[k] = nr; si[k] = ni;
        }
      }
    }
  }
}

// ---------------------------------------------------------------- LEGACY single-pass scan (ws fallback)
__global__ __launch_bounds__(256) void scan_kernel(
    const float* __restrict__ zb, const float* __restrict__ log_dt,
    const float* __restrict__ A_re, const float* __restrict__ A_im,
    const float* __restrict__ C_re, const float* __restrict__ C_im,
    float* __restrict__ yf, float* __restrict__ ybk, int blk) {
  int dir = blockIdx.y;
  int b = blockIdx.x >> 3;
  int h0 = (blockIdx.x & 7) << 5;
  int tid = threadIdx.x;
  int wv = tid >> 6, lane = tid & 63;
  int hs = lane >> 3, j = lane & 7;
  int h = h0 + wv * 8 + hs;
  float dt = expf(log_dt[blk * cH + h]);
  const float* Ar = A_re + ((size_t)blk * cH + h) * cN;
  const float* Ai = A_im + ((size_t)blk * cH + h) * cN;
  const float* Cr = C_re + (((size_t)blk * 2 + dir) * cH + h) * cN;
  const float* Ci = C_im + (((size_t)blk * 2 + dir) * cH + h) * cN;
  float wr[8], wi[8], br[8], bi[8], sr[8], si[8];
#pragma unroll
  for (int k = 0; k < 8; ++k) {
    int n = j * 8 + k;
    float are = Ar[n], aim = Ai[n];
    float e = expf(-dt * are);
    float sn, cs;
    sincosf(dt * aim, &sn, &cs);
    float w_r = e * cs, w_i = e * sn;
    float inv = 1.0f / (are * are + aim * aim);
    float xr = w_r - 1.0f, xi = w_i;
    float tr = (xi * aim - xr * are) * inv;
    float ti = (-xr * aim - xi * are) * inv;
    float cr = Cr[n], ci = Ci[n];
    br[k] = 2.0f * (cr * tr - ci * ti);
    bi[k] = 2.0f * (cr * ti + ci * tr);
    wr[k] = w_r; wi[k] = w_i;
    sr[k] = 0.0f; si[k] = 0.0f;
  }
  const float* zr = zb + ((size_t)b * cH + h) * cL;
  if (dir == 0) {
    float* yr = yf + ((size_t)b * cH + h) * cL;
    for (int l = 0; l < cL; ++l) {
      float zv = zr[l];
      float p = 0.0f;
#pragma unroll
      for (int k = 0; k < 8; ++k) {
        float nr = fmaf(wr[k], sr[k], zv);
        nr = fmaf(-wi[k], si[k], nr);
        float ni = wr[k] * si[k];
        ni = fmaf(wi[k], sr[k], ni);
        sr[k] = nr; si[k] = ni;
        p = fmaf(br[k], nr, p);
        p = fmaf(-bi[k], ni, p);
      }
      p += __shfl_xor(p, 1);
      p += __shfl_xor(p, 2);
      p += __shfl_xor(p, 4);
      if (j == 0) yr[l] = p;
    }
  } else {
    float* yr = ybk + ((size_t)b * cH + h) * cL;
    for (int l = cL - 1; l >= 0; --l) {
      float p = 0.0f;
#pragma unroll
      for (int k = 0; k < 8; ++k) {
        p = fmaf(br[k], sr[k], p);
        p = fmaf(-bi[k], si[k], p);
      }
      p += __shfl_xor(p, 1);
      p += __shfl_xor(p, 2);
      p += __shfl_xor(p, 4);
      if (j == 0) yr[l] = p;
      float zv = zr[l];
#pragma unroll
      for (int k = 0; k < 8; ++k) {
        float nr = fmaf(wr[k], sr[k], zv);
        nr = fmaf(-wi[k], si[k], nr);
        float ni = wr[k] * si[k];
        ni = fmaf(wi[k], sr[k], ni);
        sr[k] = nr; si[k] = ni;
      }
    }
  }
}

// ---------------------------------------------------------------- y = gelu(yf + yb + z*D)
__global__ __launch_bounds__(256) void gelu_kernel(const float* __restrict__ y2,
    const float* __restrict__ zz, const float* __restrict__ Dp, float* __restrict__ y1io, int blk) {
  int idx = blockIdx.x * 256 + threadIdx.x;
  int h = (idx >> 10) & (cH - 1);
  float v = y1io[idx] + y2[idx] + zz[idx] * Dp[blk * cH + h];
  y1io[idx] = 0.5f * v * (1.0f + erff(v * 0.70710678118654752f));
}

// ================================================================ GEMM core: 128(l) x 64(o) tile,
// 256 threads, 8x4 micro-tile. acc[o_i 0..3][l_i 0..7].
#define GEMM_CORE(WPTR)                                                          \
  int l0 = blockIdx.x * 128, o0 = blockIdx.y * 64, b = blockIdx.z;               \
  int tid = threadIdx.x;                                                         \
  int tx = tid & 15, ty = tid >> 4;                                              \
  const float* Gb = G + (size_t)b * cH * cL;                                     \
  float acc[4][8] = {};                                                          \
  {                                                                              \
    int ar = tid >> 6, ac = tid & 63;                                            \
    int brr = tid >> 7, bc = tid & 127;                                          \
    for (int kk = 0; kk < cH; kk += 16) {                                        \
      _Pragma("unroll")                                                          \
      for (int rr = 0; rr < 4; ++rr)                                             \
        As[ar + rr * 4][ac] = (WPTR)[(size_t)(kk + ar + rr * 4) * cH + o0 + ac]; \
      _Pragma("unroll")                                                          \
      for (int rr = 0; rr < 8; ++rr)                                             \
        Bs[brr + rr * 2][bc] = Gb[(size_t)(kk + brr + rr * 2) * cL + l0 + bc];   \
      __syncthreads();                                                           \
      _Pragma("unroll")                                                          \
      for (int k = 0; k < 16; ++k) {                                             \
        const float4 av = *(const float4*)&As[k][ty << 2];                       \
        const float4 b0 = *(const float4*)&Bs[k][tx << 3];                       \
        const float4 b1 = *(const float4*)&Bs[k][(tx << 3) + 4];                 \
        FMA8(0, av.x) FMA8(1, av.y) FMA8(2, av.z) FMA8(3, av.w)                  \
      }                                                                          \
      __syncthreads();                                                           \
    }                                                                            \
  }

#define FMA8(oi, aw)                                     \
  acc[oi][0] = fmaf(aw, b0.x, acc[oi][0]);               \
  acc[oi][1] = fmaf(aw, b0.y, acc[oi][1]);               \
  acc[oi][2] = fmaf(aw, b0.z, acc[oi][2]);               \
  acc[oi][3] = fmaf(aw, b0.w, acc[oi][3]);               \
  acc[oi][4] = fmaf(aw, b1.x, acc[oi][4]);               \
  acc[oi][5] = fmaf(aw, b1.y, acc[oi][5]);               \
  acc[oi][6] = fmaf(aw, b1.z, acc[oi][6]);               \
  acc[oi][7] = fmaf(aw, b1.w, acc[oi][7]);

// ---------------------------------------------------------------- s4-out GEMM fused with gated activation:
// g = act( (y @ Wo + bo) + (x + tb) + feat@Wf + bf ),  act(v)=tanh(v)*sigmoid(v)
__global__ __launch_bounds__(256) void gemm_act_kernel(const float* __restrict__ W,
    const float* __restrict__ bo, const float* __restrict__ G,
    const float* __restrict__ x, const float* __restrict__ tb_all,
    const float* __restrict__ features, const float* __restrict__ Wf,
    const float* __restrict__ bfb, float* __restrict__ C, int blk) {
  __shared__ float As[16][64];
  __shared__ float Bs[16][128];
  GEMM_CORE(W)
  int lbase = l0 + (tx << 3);
  float4 fv[8];
#pragma unroll
  for (int li = 0; li < 8; ++li)
    fv[li] = *(const float4*)&features[((size_t)b * cL + lbase + li) * cNF];
  const float* Wfi = Wf + (size_t)blk * cNF * cH;
  const float* tb = tb_all + ((size_t)blk * cB + b) * cH;
#pragma unroll
  for (int oi = 0; oi < 4; ++oi) {
    int oo = o0 + (ty << 2) + oi;
    float wf0 = Wfi[oo], wf1 = Wfi[cH + oo], wf2 = Wfi[2 * cH + oo], wf3 = Wfi[3 * cH + oo];
    float bb = bo[oo] + bfb[blk * cH + oo] + tb[oo];
    size_t row = ((size_t)b * cH + oo) * cL + lbase;
    const float4 x0 = *(const float4*)&x[row];
    const float4 x1 = *(const float4*)&x[row + 4];
    float xv[8] = {x0.x, x0.y, x0.z, x0.w, x1.x, x1.y, x1.z, x1.w};
    float out[8];
#pragma unroll
    for (int li = 0; li < 8; ++li) {
      float v = acc[oi][li] + bb + xv[li];
      v = fmaf(fv[li].x, wf0, v);
      v = fmaf(fv[li].y, wf1, v);
      v = fmaf(fv[li].z, wf2, v);
      v = fmaf(fv[li].w, wf3, v);
      float tv = tanhf(v);
      float sv = 1.0f / (1.0f + expf(-v));
      out[li] = tv * sv;
    }
    *(float4*)&C[row] = make_float4(out[0], out[1], out[2], out[3]);
    *(float4*)&C[row + 4] = make_float4(out[4], out[5], out[6], out[7]);
  }
}

// ---------------------------------------------------------------- dual GEMM: x += g@W1 + b1 ; skip += g@W2 + b2
__global__ __launch_bounds__(256) void gemm_dual_kernel(const float* __restrict__ W1,
    const float* __restrict__ b1, const float* __restrict__ W2, const float* __restrict__ b2,
    const float* __restrict__ G, float* __restrict__ xio, float* __restrict__ skio) {
  __shared__ float As[16][64];
  __shared__ float As2[16][64];
  __shared__ float Bs[16][128];
  int l0 = blockIdx.x * 128, o0 = blockIdx.y * 64, b = blockIdx.z;
  int tid = threadIdx.x;
  int tx = tid & 15, ty = tid >> 4;
  const float* Gb = G + (size_t)b * cH * cL;
  float acc[4][8] = {};
  float acc2[4][8] = {};
  {
    int ar = tid >> 6, ac = tid & 63;
    int brr = tid >> 7, bc = tid & 127;
    for (int kk = 0; kk < cH; kk += 16) {
#pragma unroll
      for (int rr = 0; rr < 4; ++rr) {
        As[ar + rr * 4][ac] = W1[(size_t)(kk + ar + rr * 4) * cH + o0 + ac];
        As2[ar + rr * 4][ac] = W2[(size_t)(kk + ar + rr * 4) * cH + o0 + ac];
      }
#pragma unroll
      for (int rr = 0; rr < 8; ++rr)
        Bs[brr + rr * 2][bc] = Gb[(size_t)(kk + brr + rr * 2) * cL + l0 + bc];
      __syncthreads();
#pragma unroll
      for (int k = 0; k < 16; ++k) {
        const float4 b0 = *(const float4*)&Bs[k][tx << 3];
        const float4 b1v = *(const float4*)&Bs[k][(tx << 3) + 4];
        {
          const float4 av = *(const float4*)&As[k][ty << 2];
#define FMA8D(AC, oi, aw)                          \
  AC[oi][0] = fmaf(aw, b0.x, AC[oi][0]);           \
  AC[oi][1] = fmaf(aw, b0.y, AC[oi][1]);           \
  AC[oi][2] = fmaf(aw, b0.z, AC[oi][2]);           \
  AC[oi][3] = fmaf(aw, b0.w, AC[oi][3]);           \
  AC[oi][4] = fmaf(aw, b1v.x, AC[oi][4]);          \
  AC[oi][5] = fmaf(aw, b1v.y, AC[oi][5]);          \
  AC[oi][6] = fmaf(aw, b1v.z, AC[oi][6]);          \
  AC[oi][7] = fmaf(aw, b1v.w, AC[oi][7]);
          FMA8D(acc, 0, av.x) FMA8D(acc, 1, av.y) FMA8D(acc, 2, av.z) FMA8D(acc, 3, av.w)
        }
        {
          const float4 av = *(const float4*)&As2[k][ty << 2];
          FMA8D(acc2, 0, av.x) FMA8D(acc2, 1, av.y) FMA8D(acc2, 2, av.z) FMA8D(acc2, 3, av.w)
        }
      }
      __syncthreads();
    }
  }
  int lbase = l0 + (tx << 3);
#pragma unroll
  for (int oi = 0; oi < 4; ++oi) {
    int oo = o0 + (ty << 2) + oi;
    float bb1 = b1[oo], bb2 = b2[oo];
    size_t row = ((size_t)b * cH + oo) * cL + lbase;
    float4 xv0 = *(const float4*)&xio[row];
    float4 xv1 = *(const float4*)&xio[row + 4];
    float4 sv0 = *(const float4*)&skio[row];
    float4 sv1 = *(const float4*)&skio[row + 4];
    xv0.x += acc[oi][0] + bb1; xv0.y += acc[oi][1] + bb1;
    xv0.z += acc[oi][2] + bb1; xv0.w += acc[oi][3] + bb1;
    xv1.x += acc[oi][4] + bb1; xv1.y += acc[oi][5] + bb1;
    xv1.z += acc[oi][6] + bb1; xv1.w += acc[oi][7] + bb1;
    sv0.x += acc2[oi][0] + bb2; sv0.y += acc2[oi][1] + bb2;
    sv0.z += acc2[oi][2] + bb2; sv0.w += acc2[oi][3] + bb2;
    sv1.x += acc2[oi][4] + bb2; sv1.y += acc2[oi][5] + bb2;
    sv1.z += acc2[oi][6] + bb2; sv1.w += acc2[oi][7] + bb2;
    *(float4*)&xio[row] = xv0;
    *(float4*)&xio[row + 4] = xv1;
    *(float4*)&skio[row] = sv0;
    *(float4*)&skio[row + 4] = sv1;
  }
}

// ---------------------------------------------------------------- head GEMM: C = relu(skip^T Wh1 + bh1), (B,256,L)
__global__ __launch_bounds__(256) void gemm_relu_kernel(const float* __restrict__ W,
    const float* __restrict__ bias, const float* __restrict__ G, float* __restrict__ C) {
  __shared__ float As[16][64];
  __shared__ float Bs[16][128];
  GEMM_CORE(W)
  int lbase = l0 + (tx << 3);
#pragma unroll
  for (int oi = 0; oi < 4; ++oi) {
    int oo = o0 + (ty << 2) + oi;
    float bb = bias[oo];
    size_t row = ((size_t)b * cH + oo) * cL + lbase;
    float4 v0, v1;
    v0.x = fmaxf(acc[oi][0] + bb, 0.0f); v0.y = fmaxf(acc[oi][1] + bb, 0.0f);
    v0.z = fmaxf(acc[oi][2] + bb, 0.0f); v0.w = fmaxf(acc[oi][3] + bb, 0.0f);
    v1.x = fmaxf(acc[oi][4] + bb, 0.0f); v1.y = fmaxf(acc[oi][5] + bb, 0.0f);
    v1.z = fmaxf(acc[oi][6] + bb, 0.0f); v1.w = fmaxf(acc[oi][7] + bb, 0.0f);
    *(float4*)&C[row] = v0;
    *(float4*)&C[row + 4] = v1;
  }
}

// ---------------------------------------------------------------- out = h @ Wh2 + bh2 + input
__global__ __launch_bounds__(256) void head_kernel(const float* __restrict__ hb,
    const float* __restrict__ Wh2, const float* __restrict__ bh2,
    const float* __restrict__ inp, float* __restrict__ out) {
  int idx = blockIdx.x * 256 + threadIdx.x; // B*L
  int b = idx >> 10, l = idx & (cL - 1);
  float acc = bh2[0] + inp[idx];
  const float* hr = hb + (size_t)b * cH * cL + l;
  for (int o = 0; o < cH; ++o) acc = fmaf(hr[(size_t)o * cL], Wh2[o], acc);
  out[idx] = acc;
}

// ----------------------------------------------------------------
extern "C" void kernel_launch(void* const* d_in, const int* in_sizes, int n_in,
                              void* d_out, int out_size, void* d_ws, size_t ws_size,
                              hipStream_t stream) {
  const float* input = (const float*)d_in[0];
  const float* t     = (const float*)d_in[1];
  const float* feats = (const float*)d_in[2];
  const float* W_in  = (const float*)d_in[3];
  const float* b_in  = (const float*)d_in[4];
  const float* W_t1  = (const float*)d_in[5];
  const float* b_t1  = (const float*)d_in[6];
  const float* W_t2  = (const float*)d_in[7];
  const float* b_t2  = (const float*)d_in[8];
  const float* Wh1   = (const float*)d_in[9];
  const float* bh1   = (const float*)d_in[10];
  const float* Wh2   = (const float*)d_in[11];
  const float* bh2   = (const float*)d_in[12];
  const float* ln_g  = (const float*)d_in[13];
  const float* ln_b  = (const float*)d_in[14];
  const float* logdt = (const float*)d_in[15];
  const float* A_re  = (const float*)d_in[16];
  const float* A_im  = (const float*)d_in[17];
  const float* C_re  = (const float*)d_in[18];
  const float* C_im  = (const float*)d_in[19];
  const float* Dp    = (const float*)d_in[20];
  const float* Wo_s4 = (const float*)d_in[21];
  const float* bo_s4 = (const float*)d_in[22];
  const float* Wt    = (const float*)d_in[23];
  const float* bt_   = (const float*)d_in[24];
  const float* W1    = (const float*)d_in[25];
  const float* b1    = (const float*)d_in[26];
  const float* W2    = (const float*)d_in[27];
  const float* b2    = (const float*)d_in[28];
  const float* Wf    = (const float*)d_in[29];
  const float* bf_   = (const float*)d_in[30];

  float* ws = (float*)d_ws;
  float* xb   = ws;            // x (B,H,L)
  float* skb  = ws + SZ;       // skip
  float* zbuf = ws + 2 * SZ;   // LN out -> later g buffer
  float* yb   = ws + 3 * SZ;   // fwd conv partial -> gelu out -> head relu out
  float* y2b  = ws + 4 * SZ;   // bwd conv partial
  float* tbb  = ws + 5 * SZ;   // (NB,B,H) = 24576 floats
  // chunked-scan extras
  size_t off = 5 * SZ + 32768;                 // float offset, 16B-aligned
  float4* Pbuf = (float4*)(ws + off);          // 2*cH*cN float4 = 131072 floats
  float2* PWb  = (float2*)(ws + off + 131072); // cH*cN float2 = 32768 floats
  float2* Ebuf = (float2*)(ws + off + 131072 + 32768); // 2*cC*cB*cH*cN float2
  const size_t NEED = (off + 131072 + 32768 + (size_t)2 * cC * cB * cH * cN * 2) * 4;
  const bool chunked = ws_size >= NEED;

  dim3 ggrid(cL / 128, cH / 64, cB);
  dim3 sgrid(cC, cB * (cH / 32), 2);

  temb_kernel<<<cB, 256, 0, stream>>>(t, W_t1, b_t1, W_t2, b_t2, Wt, bt_, tbb);
  init_kernel<<<(int)(SZ / 256), 256, 0, stream>>>(input, W_in, b_in, xb, skb);

  for (int i = 0; i < cNB; ++i) {
    pre_ln_kernel<<<cB * (cL / 64), 256, 0, stream>>>(xb, tbb, ln_g, ln_b, zbuf, i);
    if (chunked) {
      s4param_kernel<<<128, 256, 0, stream>>>(logdt, A_re, A_im, C_re, C_im, Pbuf, PWb, i);
      scanA1_kernel<<<sgrid, 256, 0, stream>>>(zbuf, Pbuf, Ebuf);
      scanA2_kernel<<<sgrid, 256, 0, stream>>>(zbuf, Pbuf, PWb, Ebuf, yb, y2b);
    } else {
      scan_kernel<<<dim3(cB * (cH / 32), 2), 256, 0, stream>>>(zbuf, logdt, A_re, A_im, C_re, C_im, yb, y2b, i);
    }
    gelu_kernel<<<(int)(SZ / 256), 256, 0, stream>>>(y2b, zbuf, Dp, yb, i);
    gemm_act_kernel<<<ggrid, 256, 0, stream>>>(
        Wo_s4 + (size_t)i * cH * cH, bo_s4 + i * cH, yb, xb, tbb, feats, Wf, bf_, zbuf, i);
    gemm_dual_kernel<<<ggrid, 256, 0, stream>>>(
        W1 + (size_t)i * cH * cH, b1 + i * cH, W2 + (size_t)i * cH * cH, b2 + i * cH,
        zbuf, xb, skb);
  }

  // head: h = relu(skip^T Wh1 + bh1) stored (B,256,L) in yb, then scalar head
  gemm_relu_kernel<<<ggrid, 256, 0, stream>>>(Wh1, bh1, skb, yb);
  head_kernel<<<(cB * cL) / 256, 256, 0, stream>>>(yb, Wh2, bh2, input, (float*)d_out);
}

// Round 8
// 1932.094 us; speedup vs baseline: 1.4527x; 1.0051x over previous
//
#include <hip/hip_runtime.h>
#include <cmath>

constexpr int cB = 16, cL = 1024, cH = 256, cN = 64, cNB = 6, cNF = 4;
constexpr int cC = 8, cLc = cL / cC;           // chunked scan: 8 chunks of 128
constexpr size_t SZ = (size_t)cB * cH * cL;    // 4,194,304 elements per activation buffer

__device__ __forceinline__ float gelu_f(float v) {
  return 0.5f * v * (1.0f + erff(v * 0.70710678118654752f));
}

// ---------------------------------------------------------------- temb + tb
__global__ __launch_bounds__(256) void temb_kernel(
    const float* __restrict__ t, const float* __restrict__ Wt1, const float* __restrict__ bt1,
    const float* __restrict__ Wt2, const float* __restrict__ bt2,
    const float* __restrict__ Wt, const float* __restrict__ btb, float* __restrict__ tb) {
  __shared__ float e0[128], h1[256], h2[256];
  int b = blockIdx.x, tid = threadIdx.x;
  if (tid < 64) {
    float fr = expf((float)tid * (-logf(10000.0f) / 63.0f));
    float ang = t[b] * fr;
    e0[tid] = sinf(ang);
    e0[tid + 64] = cosf(ang);
  }
  __syncthreads();
  float a = bt1[tid];
  for (int k = 0; k < 128; ++k) a = fmaf(e0[k], Wt1[k * cH + tid], a);
  h1[tid] = a / (1.0f + expf(-a));   // silu
  __syncthreads();
  a = bt2[tid];
  for (int k = 0; k < 256; ++k) a = fmaf(h1[k], Wt2[k * cH + tid], a);
  h2[tid] = a / (1.0f + expf(-a));
  __syncthreads();
  for (int i = 0; i < cNB; ++i) {
    float acc = btb[i * cH + tid];
    const float* w = Wt + (size_t)i * cH * cH;
    for (int k = 0; k < 256; ++k) acc = fmaf(h2[k], w[k * cH + tid], acc);
    tb[((size_t)i * cB + b) * cH + tid] = acc;
  }
}

// ---------------------------------------------------------------- x init + skip=0
__global__ __launch_bounds__(256) void init_kernel(const float* __restrict__ inp,
    const float* __restrict__ Win, const float* __restrict__ bin,
    float* __restrict__ x, float* __restrict__ skip) {
  int idx = blockIdx.x * 256 + threadIdx.x;
  int l = idx & (cL - 1);
  int h = (idx >> 10) & (cH - 1);
  int b = idx >> 18;
  float v = fmaf(inp[b * cL + l], Win[h], bin[h]);
  x[idx] = v > 0.0f ? v : 0.0f;
  skip[idx] = 0.0f;
}

// ---------------------------------------------------------------- z = LN_H(x + tb)
__global__ __launch_bounds__(256) void pre_ln_kernel(const float* __restrict__ x,
    const float* __restrict__ tb_all, const float* __restrict__ ln_g, const float* __restrict__ ln_b,
    float* __restrict__ z, int blk) {
  __shared__ float red[8][64];
  __shared__ float mur[64], rsr[64];
  int b = blockIdx.x >> 4;
  int l0 = (blockIdx.x & 15) << 6;
  int lq = threadIdx.x & 63, hq = threadIdx.x >> 6; // 4 h-groups of 64
  int l = l0 + lq;
  const float* tb = tb_all + ((size_t)blk * cB + b) * cH;
  size_t base = ((size_t)b * cH + hq * 64) * cL + l;
  float s = 0.0f, s2 = 0.0f;
  for (int hh = 0; hh < 64; ++hh) {
    float v = x[base + (size_t)hh * cL] + tb[hq * 64 + hh];
    s += v;
    s2 = fmaf(v, v, s2);
  }
  red[hq][lq] = s;
  red[4 + hq][lq] = s2;
  __syncthreads();
  if (hq == 0) {
    float st = red[0][lq] + red[1][lq] + red[2][lq] + red[3][lq];
    float s2t = red[4][lq] + red[5][lq] + red[6][lq] + red[7][lq];
    float mu = st * (1.0f / cH);
    float var = s2t * (1.0f / cH) - mu * mu;
    mur[lq] = mu;
    rsr[lq] = rsqrtf(var + 1e-5f);
  }
  __syncthreads();
  float mu = mur[lq], r = rsr[lq];
  const float* g = ln_g + blk * cH;
  const float* be = ln_b + blk * cH;
  for (int hh = 0; hh < 64; ++hh) {
    int h = hq * 64 + hh;
    float v = (x[base + (size_t)hh * cL] + tb[h] - mu) * r;
    z[base + (size_t)hh * cL] = fmaf(v, g[h], be[h]);
  }
}

// ---------------------------------------------------------------- S4 per-block params
__global__ __launch_bounds__(256) void s4param_kernel(
    const float* __restrict__ logdt, const float* __restrict__ Are, const float* __restrict__ Aim,
    const float* __restrict__ Cre, const float* __restrict__ Cim,
    float4* __restrict__ P, float2* __restrict__ PW, int blk) {
  int idx = blockIdx.x * 256 + threadIdx.x;      // (dir*cH+h)*cN+n, 32768 total
  int n = idx & (cN - 1);
  int h = (idx >> 6) & (cH - 1);
  int dir = idx >> 14;
  float dt = expf(logdt[blk * cH + h]);
  float are = Are[((size_t)blk * cH + h) * cN + n];
  float aim = Aim[((size_t)blk * cH + h) * cN + n];
  float e = expf(-dt * are);
  float sn, cs;
  sincosf(dt * aim, &sn, &cs);
  float wr = e * cs, wi = e * sn;
  float inv = 1.0f / (are * are + aim * aim);
  float xr = wr - 1.0f, xi = wi;
  float tr = (xi * aim - xr * are) * inv;
  float ti = (-xr * aim - xi * are) * inv;
  float cr = Cre[(((size_t)blk * 2 + dir) * cH + h) * cN + n];
  float ci = Cim[(((size_t)blk * 2 + dir) * cH + h) * cN + n];
  float br = 2.0f * (cr * tr - ci * ti);
  float bi = 2.0f * (cr * ti + ci * tr);
  P[idx] = make_float4(wr, wi, br, bi);
  if (dir == 0) {
    float rr = wr, ri = wi;                      // w^128 by 7 squarings
#pragma unroll
    for (int q = 0; q < 7; ++q) {
      float nr = rr * rr - ri * ri;
      ri = 2.0f * rr * ri;
      rr = nr;
    }
    PW[h * cN + n] = make_float2(rr, ri);
  }
}

// ---------------------------------------------------------------- scan A1: per-chunk end states, BOTH dirs
// grid (cC, cB*cH/32). wave: 8 lanes/channel x 8 states/lane, 8 channels/wave.
__global__ __launch_bounds__(256) void scanA1_kernel(const float* __restrict__ zb,
    const float4* __restrict__ P, float2* __restrict__ E) {
  int c = blockIdx.x, bh = blockIdx.y;
  int b = bh >> 3, h0 = (bh & 7) << 5;
  int tid = threadIdx.x, wv = tid >> 6, lane = tid & 63;
  int hs = lane >> 3, j = lane & 7;
  int h = h0 + wv * 8 + hs;
  const float* zr = zb + ((size_t)b * cH + h) * cL;
  int c0 = c * cLc;
  // ---- dir 0 (fwd)
  {
    float wr[8], wi[8], sr[8] = {}, si[8] = {};
    const float4* Ph = P + (size_t)h * cN + j * 8;
#pragma unroll
    for (int k = 0; k < 8; ++k) { float4 p4 = Ph[k]; wr[k] = p4.x; wi[k] = p4.y; }
    for (int m = 0; m < cLc / 4; ++m) {
      float4 z4 = *(const float4*)&zr[c0 + (m << 2)];
#pragma unroll
      for (int q = 0; q < 4; ++q) {
        float zv = q == 0 ? z4.x : q == 1 ? z4.y : q == 2 ? z4.z : z4.w;
#pragma unroll
        for (int k = 0; k < 8; ++k) {
          float nr = fmaf(wr[k], sr[k], zv);
          nr = fmaf(-wi[k], si[k], nr);
          float ni = wr[k] * si[k];
          ni = fmaf(wi[k], sr[k], ni);
          sr[k] = nr; si[k] = ni;
        }
      }
    }
    float2* Eo = E + ((((size_t)0 * cC + c) * cB + b) * cH + h) * cN + j * 8;
#pragma unroll
    for (int k = 0; k < 8; ++k) Eo[k] = make_float2(sr[k], si[k]);
  }
  // ---- dir 1 (bwd)
  {
    float wr[8], wi[8], sr[8] = {}, si[8] = {};
    const float4* Ph = P + ((size_t)cH + h) * cN + j * 8;
#pragma unroll
    for (int k = 0; k < 8; ++k) { float4 p4 = Ph[k]; wr[k] = p4.x; wi[k] = p4.y; }
    for (int m = cLc / 4 - 1; m >= 0; --m) {
      float4 z4 = *(const float4*)&zr[c0 + (m << 2)];
#pragma unroll
      for (int q = 3; q >= 0; --q) {
        float zv = q == 0 ? z4.x : q == 1 ? z4.y : q == 2 ? z4.z : z4.w;
#pragma unroll
        for (int k = 0; k < 8; ++k) {
          float nr = fmaf(wr[k], sr[k], zv);
          nr = fmaf(-wi[k], si[k], nr);
          float ni = wr[k] * si[k];
          ni = fmaf(wi[k], sr[k], ni);
          sr[k] = nr; si[k] = ni;
        }
      }
    }
    float2* Eo = E + ((((size_t)cC + c) * cB + b) * cH + h) * cN + j * 8;
#pragma unroll
    for (int k = 0; k < 8; ++k) Eo[k] = make_float2(sr[k], si[k]);
  }
}

// ---------------------------------------------------------------- scan B: transform E in-place into per-chunk carries.
// One thread owns one (dir,b,h,n) series; 8-step sequential fold.
__global__ __launch_bounds__(256) void scanB_kernel(float2* __restrict__ E,
    const float2* __restrict__ PW) {
  int idx = blockIdx.x * 256 + threadIdx.x;  // ((dir*cB+b)*cH+h)*cN+n, 524288 total
  int n = idx & (cN - 1);
  int h = (idx >> 6) & (cH - 1);
  int b = (idx >> 14) & (cB - 1);
  int dir = idx >> 18;
  float2 q2 = PW[h * cN + n];
  float qr = q2.x, qi = q2.y;
  const size_t cs = (size_t)cB * cH * cN;
  size_t e0 = ((((size_t)dir * cC) * cB + b) * cH + h) * cN + n;
  float sr = 0.0f, si = 0.0f;
  if (dir == 0) {
    for (int cc = 0; cc < cC; ++cc) {
      float2 e = E[e0 + cc * cs];
      E[e0 + cc * cs] = make_float2(sr, si);
      float nr = fmaf(qr, sr, e.x); nr = fmaf(-qi, si, nr);
      float ni = fmaf(qr, si, e.y); ni = fmaf(qi, sr, ni);
      sr = nr; si = ni;
    }
  } else {
    for (int cc = cC - 1; cc >= 0; --cc) {
      float2 e = E[e0 + cc * cs];
      E[e0 + cc * cs] = make_float2(sr, si);
      float nr = fmaf(qr, sr, e.x); nr = fmaf(-qi, si, nr);
      float ni = fmaf(qr, si, e.y); ni = fmaf(qi, sr, ni);
      sr = nr; si = ni;
    }
  }
}

// ---------------------------------------------------------------- scan A2: both dirs from carries + combine + z*D + gelu
// grid (cC, cB*cH/32). Writes y = gelu(yf+yb+z*D) directly (gelu kernel fused away).
__global__ __launch_bounds__(256) void scanA2_kernel(const float* __restrict__ zb,
    const float4* __restrict__ P, const float2* __restrict__ E, const float* __restrict__ Dp,
    float* __restrict__ y, int blk) {
  __shared__ float acc_lds[32][cLc + 1];   // +1 pad: j==0 writers hit distinct banks
  int c = blockIdx.x, bh = blockIdx.y;
  int b = bh >> 3, h0 = (bh & 7) << 5;
  int tid = threadIdx.x, wv = tid >> 6, lane = tid & 63;
  int hs = lane >> 3, j = lane & 7;
  int lch = wv * 8 + hs;
  int h = h0 + lch;
  const float* zr = zb + ((size_t)b * cH + h) * cL;
  int c0 = c * cLc;
  // ---- dir 0 (fwd): carry -> scan -> yf into LDS
  {
    float wr[8], wi[8], br[8], bi[8], sr[8], si[8];
    const float4* Ph = P + (size_t)h * cN + j * 8;
    const float2* Cc = E + ((((size_t)0 * cC + c) * cB + b) * cH + h) * cN + j * 8;
#pragma unroll
    for (int k = 0; k < 8; ++k) {
      float4 p4 = Ph[k];
      wr[k] = p4.x; wi[k] = p4.y; br[k] = p4.z; bi[k] = p4.w;
      float2 e2 = Cc[k];
      sr[k] = e2.x; si[k] = e2.y;
    }
    for (int m = 0; m < cLc / 4; ++m) {
      float4 z4 = *(const float4*)&zr[c0 + (m << 2)];
#pragma unroll
      for (int q = 0; q < 4; ++q) {
        float zv = q == 0 ? z4.x : q == 1 ? z4.y : q == 2 ? z4.z : z4.w;
        float p = 0.0f;
#pragma unroll
        for (int k = 0; k < 8; ++k) {
          float nr = fmaf(wr[k], sr[k], zv);
          nr = fmaf(-wi[k], si[k], nr);
          float ni = wr[k] * si[k];
          ni = fmaf(wi[k], sr[k], ni);
          sr[k] = nr; si[k] = ni;
          p = fmaf(br[k], nr, p);
          p = fmaf(-bi[k], ni, p);
        }
        p += __shfl_xor(p, 1);
        p += __shfl_xor(p, 2);
        p += __shfl_xor(p, 4);
        if (j == 0) acc_lds[lch][(m << 2) + q] = p;
      }
    }
  }
  // ---- dir 1 (bwd): carry -> scan -> accumulate into LDS (same-thread RMW, no barrier needed)
  {
    float wr[8], wi[8], br[8], bi[8], sr[8], si[8];
    const float4* Ph = P + ((size_t)cH + h) * cN + j * 8;
    const float2* Cc = E + ((((size_t)cC + c) * cB + b) * cH + h) * cN + j * 8;
#pragma unroll
    for (int k = 0; k < 8; ++k) {
      float4 p4 = Ph[k];
      wr[k] = p4.x; wi[k] = p4.y; br[k] = p4.z; bi[k] = p4.w;
      float2 e2 = Cc[k];
      sr[k] = e2.x; si[k] = e2.y;
    }
    for (int m = cLc / 4 - 1; m >= 0; --m) {
      float4 z4 = *(const float4*)&zr[c0 + (m << 2)];
#pragma unroll
      for (int q = 3; q >= 0; --q) {
        float zv = q == 0 ? z4.x : q == 1 ? z4.y : q == 2 ? z4.z : z4.w;
        float p = 0.0f;
#pragma unroll
        for (int k = 0; k < 8; ++k) {
          p = fmaf(br[k], sr[k], p);
          p = fmaf(-bi[k], si[k], p);
        }
        p += __shfl_xor(p, 1);
        p += __shfl_xor(p, 2);
        p += __shfl_xor(p, 4);
        if (j == 0) acc_lds[lch][(m << 2) + q] += p;
#pragma unroll
        for (int k = 0; k < 8; ++k) {
          float nr = fmaf(wr[k], sr[k], zv);
          nr = fmaf(-wi[k], si[k], nr);
          float ni = wr[k] * si[k];
          ni = fmaf(wi[k], sr[k], ni);
          sr[k] = nr; si[k] = ni;
        }
      }
    }
  }
  __syncthreads();
  // ---- combine: v = yf+yb + z*D, gelu, vectorized store
  int lc2 = tid >> 3, part = tid & 7;
  int hh = h0 + lc2;
  float Dv = Dp[blk * cH + hh];
  const float* zrow = zb + ((size_t)b * cH + hh) * cL + c0;
  float* yrow = y + ((size_t)b * cH + hh) * cL + c0;
#pragma unroll
  for (int g = 0; g < 4; ++g) {
    int l = part * 16 + g * 4;
    float4 z4 = *(const float4*)&zrow[l];
    float4 o;
    o.x = gelu_f(acc_lds[lc2][l + 0] + z4.x * Dv);
    o.y = gelu_f(acc_lds[lc2][l + 1] + z4.y * Dv);
    o.z = gelu_f(acc_lds[lc2][l + 2] + z4.z * Dv);
    o.w = gelu_f(acc_lds[lc2][l + 3] + z4.w * Dv);
    *(float4*)&yrow[l] = o;
  }
}

// ---------------------------------------------------------------- LEGACY single-pass scan (ws fallback)
__global__ __launch_bounds__(256) void scan_kernel(
    const float* __restrict__ zb, const float* __restrict__ log_dt,
    const float* __restrict__ A_re, const float* __restrict__ A_im,
    const float* __restrict__ C_re, const float* __restrict__ C_im,
    float* __restrict__ yf, float* __restrict__ ybk, int blk) {
  int dir = blockIdx.y;
  int b = blockIdx.x >> 3;
  int h0 = (blockIdx.x & 7) << 5;
  int tid = threadIdx.x;
  int wv = tid >> 6, lane = tid & 63;
  int hs = lane >> 3, j = lane & 7;
  int h = h0 + wv * 8 + hs;
  float dt = expf(log_dt[blk * cH + h]);
  const float* Ar = A_re + ((size_t)blk * cH + h) * cN;
  const float* Ai = A_im + ((size_t)blk * cH + h) * cN;
  const float* Cr = C_re + (((size_t)blk * 2 + dir) * cH + h) * cN;
  const float* Ci = C_im + (((size_t)blk * 2 + dir) * cH + h) * cN;
  float wr[8], wi[8], br[8], bi[8], sr[8], si[8];
#pragma unroll
  for (int k = 0; k < 8; ++k) {
    int n = j * 8 + k;
    float are = Ar[n], aim = Ai[n];
    float e = expf(-dt * are);
    float sn, cs;
    sincosf(dt * aim, &sn, &cs);
    float w_r = e * cs, w_i = e * sn;
    float inv = 1.0f / (are * are + aim * aim);
    float xr = w_r - 1.0f, xi = w_i;
    float tr = (xi * aim - xr * are) * inv;
    float ti = (-xr * aim - xi * are) * inv;
    float cr = Cr[n], ci = Ci[n];
    br[k] = 2.0f * (cr * tr - ci * ti);
    bi[k] = 2.0f * (cr * ti + ci * tr);
    wr[k] = w_r; wi[k] = w_i;
    sr[k] = 0.0f; si[k] = 0.0f;
  }
  const float* zr = zb + ((size_t)b * cH + h) * cL;
  if (dir == 0) {
    float* yr = yf + ((size_t)b * cH + h) * cL;
    for (int l = 0; l < cL; ++l) {
      float zv = zr[l];
      float p = 0.0f;
#pragma unroll
      for (int k = 0; k < 8; ++k) {
        float nr = fmaf(wr[k], sr[k], zv);
        nr = fmaf(-wi[k], si[k], nr);
        float ni = wr[k] * si[k];
        ni = fmaf(wi[k], sr[k], ni);
        sr[k] = nr; si[k] = ni;
        p = fmaf(br[k], nr, p);
        p = fmaf(-bi[k], ni, p);
      }
      p += __shfl_xor(p, 1);
      p += __shfl_xor(p, 2);
      p += __shfl_xor(p, 4);
      if (j == 0) yr[l] = p;
    }
  } else {
    float* yr = ybk + ((size_t)b * cH + h) * cL;
    for (int l = cL - 1; l >= 0; --l) {
      float p = 0.0f;
#pragma unroll
      for (int k = 0; k < 8; ++k) {
        p = fmaf(br[k], sr[k], p);
        p = fmaf(-bi[k], si[k], p);
      }
      p += __shfl_xor(p, 1);
      p += __shfl_xor(p, 2);
      p += __shfl_xor(p, 4);
      if (j == 0) yr[l] = p;
      float zv = zr[l];
#pragma unroll
      for (int k = 0; k < 8; ++k) {
        float nr = fmaf(wr[k], sr[k], zv);
        nr = fmaf(-wi[k], si[k], nr);
        float ni = wr[k] * si[k];
        ni = fmaf(wi[k], sr[k], ni);
        sr[k] = nr; si[k] = ni;
      }
    }
  }
}

// ---------------------------------------------------------------- y = gelu(yf + yb + z*D)  (legacy path only)
__global__ __launch_bounds__(256) void gelu_kernel(const float* __restrict__ y2,
    const float* __restrict__ zz, const float* __restrict__ Dp, float* __restrict__ y1io, int blk) {
  int idx = blockIdx.x * 256 + threadIdx.x;
  int h = (idx >> 10) & (cH - 1);
  float v = y1io[idx] + y2[idx] + zz[idx] * Dp[blk * cH + h];
  y1io[idx] = gelu_f(v);
}

// ================================================================ GEMM core: 128(l) x 64(o) tile,
// 256 threads, 8x4 micro-tile. acc[o_i 0..3][l_i 0..7].
#define GEMM_CORE(WPTR)                                                          \
  int l0 = blockIdx.x * 128, o0 = blockIdx.y * 64, b = blockIdx.z;               \
  int tid = threadIdx.x;                                                         \
  int tx = tid & 15, ty = tid >> 4;                                              \
  const float* Gb = G + (size_t)b * cH * cL;                                     \
  float acc[4][8] = {};                                                          \
  {                                                                              \
    int ar = tid >> 6, ac = tid & 63;                                            \
    int brr = tid >> 7, bc = tid & 127;                                          \
    for (int kk = 0; kk < cH; kk += 16) {                                        \
      _Pragma("unroll")                                                          \
      for (int rr = 0; rr < 4; ++rr)                                             \
        As[ar + rr * 4][ac] = (WPTR)[(size_t)(kk + ar + rr * 4) * cH + o0 + ac]; \
      _Pragma("unroll")                                                          \
      for (int rr = 0; rr < 8; ++rr)                                             \
        Bs[brr + rr * 2][bc] = Gb[(size_t)(kk + brr + rr * 2) * cL + l0 + bc];   \
      __syncthreads();                                                           \
      _Pragma("unroll")                                                          \
      for (int k = 0; k < 16; ++k) {                                             \
        const float4 av = *(const float4*)&As[k][ty << 2];                       \
        const float4 b0 = *(const float4*)&Bs[k][tx << 3];                       \
        const float4 b1 = *(const float4*)&Bs[k][(tx << 3) + 4];                 \
        FMA8(0, av.x) FMA8(1, av.y) FMA8(2, av.z) FMA8(3, av.w)                  \
      }                                                                          \
      __syncthreads();                                                           \
    }                                                                            \
  }

#define FMA8(oi, aw)                                     \
  acc[oi][0] = fmaf(aw, b0.x, acc[oi][0]);               \
  acc[oi][1] = fmaf(aw, b0.y, acc[oi][1]);               \
  acc[oi][2] = fmaf(aw, b0.z, acc[oi][2]);               \
  acc[oi][3] = fmaf(aw, b0.w, acc[oi][3]);               \
  acc[oi][4] = fmaf(aw, b1.x, acc[oi][4]);               \
  acc[oi][5] = fmaf(aw, b1.y, acc[oi][5]);               \
  acc[oi][6] = fmaf(aw, b1.z, acc[oi][6]);               \
  acc[oi][7] = fmaf(aw, b1.w, acc[oi][7]);

// ---------------------------------------------------------------- s4-out GEMM fused with gated activation
__global__ __launch_bounds__(256) void gemm_act_kernel(const float* __restrict__ W,
    const float* __restrict__ bo, const float* __restrict__ G,
    const float* __restrict__ x, const float* __restrict__ tb_all,
    const float* __restrict__ features, const float* __restrict__ Wf,
    const float* __restrict__ bfb, float* __restrict__ C, int blk) {
  __shared__ float As[16][64];
  __shared__ float Bs[16][128];
  GEMM_CORE(W)
  int lbase = l0 + (tx << 3);
  float4 fv[8];
#pragma unroll
  for (int li = 0; li < 8; ++li)
    fv[li] = *(const float4*)&features[((size_t)b * cL + lbase + li) * cNF];
  const float* Wfi = Wf + (size_t)blk * cNF * cH;
  const float* tb = tb_all + ((size_t)blk * cB + b) * cH;
#pragma unroll
  for (int oi = 0; oi < 4; ++oi) {
    int oo = o0 + (ty << 2) + oi;
    float wf0 = Wfi[oo], wf1 = Wfi[cH + oo], wf2 = Wfi[2 * cH + oo], wf3 = Wfi[3 * cH + oo];
    float bb = bo[oo] + bfb[blk * cH + oo] + tb[oo];
    size_t row = ((size_t)b * cH + oo) * cL + lbase;
    const float4 x0 = *(const float4*)&x[row];
    const float4 x1 = *(const float4*)&x[row + 4];
    float xv[8] = {x0.x, x0.y, x0.z, x0.w, x1.x, x1.y, x1.z, x1.w};
    float out[8];
#pragma unroll
    for (int li = 0; li < 8; ++li) {
      float v = acc[oi][li] + bb + xv[li];
      v = fmaf(fv[li].x, wf0, v);
      v = fmaf(fv[li].y, wf1, v);
      v = fmaf(fv[li].z, wf2, v);
      v = fmaf(fv[li].w, wf3, v);
      float tv = tanhf(v);
      float sv = 1.0f / (1.0f + expf(-v));
      out[li] = tv * sv;
    }
    *(float4*)&C[row] = make_float4(out[0], out[1], out[2], out[3]);
    *(float4*)&C[row + 4] = make_float4(out[4], out[5], out[6], out[7]);
  }
}

// ---------------------------------------------------------------- dual GEMM: x += g@W1 + b1 ; skip += g@W2 + b2
__global__ __launch_bounds__(256) void gemm_dual_kernel(const float* __restrict__ W1,
    const float* __restrict__ b1, const float* __restrict__ W2, const float* __restrict__ b2,
    const float* __restrict__ G, float* __restrict__ xio, float* __restrict__ skio) {
  __shared__ float As[16][64];
  __shared__ float As2[16][64];
  __shared__ float Bs[16][128];
  int l0 = blockIdx.x * 128, o0 = blockIdx.y * 64, b = blockIdx.z;
  int tid = threadIdx.x;
  int tx = tid & 15, ty = tid >> 4;
  const float* Gb = G + (size_t)b * cH * cL;
  float acc[4][8] = {};
  float acc2[4][8] = {};
  {
    int ar = tid >> 6, ac = tid & 63;
    int brr = tid >> 7, bc = tid & 127;
    for (int kk = 0; kk < cH; kk += 16) {
#pragma unroll
      for (int rr = 0; rr < 4; ++rr) {
        As[ar + rr * 4][ac] = W1[(size_t)(kk + ar + rr * 4) * cH + o0 + ac];
        As2[ar + rr * 4][ac] = W2[(size_t)(kk + ar + rr * 4) * cH + o0 + ac];
      }
#pragma unroll
      for (int rr = 0; rr < 8; ++rr)
        Bs[brr + rr * 2][bc] = Gb[(size_t)(kk + brr + rr * 2) * cL + l0 + bc];
      __syncthreads();
#pragma unroll
      for (int k = 0; k < 16; ++k) {
        const float4 b0 = *(const float4*)&Bs[k][tx << 3];
        const float4 b1v = *(const float4*)&Bs[k][(tx << 3) + 4];
        {
          const float4 av = *(const float4*)&As[k][ty << 2];
#define FMA8D(AC, oi, aw)                          \
  AC[oi][0] = fmaf(aw, b0.x, AC[oi][0]);           \
  AC[oi][1] = fmaf(aw, b0.y, AC[oi][1]);           \
  AC[oi][2] = fmaf(aw, b0.z, AC[oi][2]);           \
  AC[oi][3] = fmaf(aw, b0.w, AC[oi][3]);           \
  AC[oi][4] = fmaf(aw, b1v.x, AC[oi][4]);          \
  AC[oi][5] = fmaf(aw, b1v.y, AC[oi][5]);          \
  AC[oi][6] = fmaf(aw, b1v.z, AC[oi][6]);          \
  AC[oi][7] = fmaf(aw, b1v.w, AC[oi][7]);
          FMA8D(acc, 0, av.x) FMA8D(acc, 1, av.y) FMA8D(acc, 2, av.z) FMA8D(acc, 3, av.w)
        }
        {
          const float4 av = *(const float4*)&As2[k][ty << 2];
          FMA8D(acc2, 0, av.x) FMA8D(acc2, 1, av.y) FMA8D(acc2, 2, av.z) FMA8D(acc2, 3, av.w)
        }
      }
      __syncthreads();
    }
  }
  int lbase = l0 + (tx << 3);
#pragma unroll
  for (int oi = 0; oi < 4; ++oi) {
    int oo = o0 + (ty << 2) + oi;
    float bb1 = b1[oo], bb2 = b2[oo];
    size_t row = ((size_t)b * cH + oo) * cL + lbase;
    float4 xv0 = *(const float4*)&xio[row];
    float4 xv1 = *(const float4*)&xio[row + 4];
    float4 sv0 = *(const float4*)&skio[row];
    float4 sv1 = *(const float4*)&skio[row + 4];
    xv0.x += acc[oi][0] + bb1; xv0.y += acc[oi][1] + bb1;
    xv0.z += acc[oi][2] + bb1; xv0.w += acc[oi][3] + bb1;
    xv1.x += acc[oi][4] + bb1; xv1.y += acc[oi][5] + bb1;
    xv1.z += acc[oi][6] + bb1; xv1.w += acc[oi][7] + bb1;
    sv0.x += acc2[oi][0] + bb2; sv0.y += acc2[oi][1] + bb2;
    sv0.z += acc2[oi][2] + bb2; sv0.w += acc2[oi][3] + bb2;
    sv1.x += acc2[oi][4] + bb2; sv1.y += acc2[oi][5] + bb2;
    sv1.z += acc2[oi][6] + bb2; sv1.w += acc2[oi][7] + bb2;
    *(float4*)&xio[row] = xv0;
    *(float4*)&xio[row + 4] = xv1;
    *(float4*)&skio[row] = sv0;
    *(float4*)&skio[row + 4] = sv1;
  }
}

// ---------------------------------------------------------------- head GEMM: C = relu(skip^T Wh1 + bh1), (B,256,L)
__global__ __launch_bounds__(256) void gemm_relu_kernel(const float* __restrict__ W,
    const float* __restrict__ bias, const float* __restrict__ G, float* __restrict__ C) {
  __shared__ float As[16][64];
  __shared__ float Bs[16][128];
  GEMM_CORE(W)
  int lbase = l0 + (tx << 3);
#pragma unroll
  for (int oi = 0; oi < 4; ++oi) {
    int oo = o0 + (ty << 2) + oi;
    float bb = bias[oo];
    size_t row = ((size_t)b * cH + oo) * cL + lbase;
    float4 v0, v1;
    v0.x = fmaxf(acc[oi][0] + bb, 0.0f); v0.y = fmaxf(acc[oi][1] + bb, 0.0f);
    v0.z = fmaxf(acc[oi][2] + bb, 0.0f); v0.w = fmaxf(acc[oi][3] + bb, 0.0f);
    v1.x = fmaxf(acc[oi][4] + bb, 0.0f); v1.y = fmaxf(acc[oi][5] + bb, 0.0f);
    v1.z = fmaxf(acc[oi][6] + bb, 0.0f); v1.w = fmaxf(acc[oi][7] + bb, 0.0f);
    *(float4*)&C[row] = v0;
    *(float4*)&C[row + 4] = v1;
  }
}

// ---------------------------------------------------------------- out = h @ Wh2 + bh2 + input
__global__ __launch_bounds__(256) void head_kernel(const float* __restrict__ hb,
    const float* __restrict__ Wh2, const float* __restrict__ bh2,
    const float* __restrict__ inp, float* __restrict__ out) {
  int idx = blockIdx.x * 256 + threadIdx.x; // B*L
  int b = idx >> 10, l = idx & (cL - 1);
  float acc = bh2[0] + inp[idx];
  const float* hr = hb + (size_t)b * cH * cL + l;
  for (int o = 0; o < cH; ++o) acc = fmaf(hr[(size_t)o * cL], Wh2[o], acc);
  out[idx] = acc;
}

// ----------------------------------------------------------------
extern "C" void kernel_launch(void* const* d_in, const int* in_sizes, int n_in,
                              void* d_out, int out_size, void* d_ws, size_t ws_size,
                              hipStream_t stream) {
  const float* input = (const float*)d_in[0];
  const float* t     = (const float*)d_in[1];
  const float* feats = (const float*)d_in[2];
  const float* W_in  = (const float*)d_in[3];
  const float* b_in  = (const float*)d_in[4];
  const float* W_t1  = (const float*)d_in[5];
  const float* b_t1  = (const float*)d_in[6];
  const float* W_t2  = (const float*)d_in[7];
  const float* b_t2  = (const float*)d_in[8];
  const float* Wh1   = (const float*)d_in[9];
  const float* bh1   = (const float*)d_in[10];
  const float* Wh2   = (const float*)d_in[11];
  const float* bh2   = (const float*)d_in[12];
  const float* ln_g  = (const float*)d_in[13];
  const float* ln_b  = (const float*)d_in[14];
  const float* logdt = (const float*)d_in[15];
  const float* A_re  = (const float*)d_in[16];
  const float* A_im  = (const float*)d_in[17];
  const float* C_re  = (const float*)d_in[18];
  const float* C_im  = (const float*)d_in[19];
  const float* Dp    = (const float*)d_in[20];
  const float* Wo_s4 = (const float*)d_in[21];
  const float* bo_s4 = (const float*)d_in[22];
  const float* Wt    = (const float*)d_in[23];
  const float* bt_   = (const float*)d_in[24];
  const float* W1    = (const float*)d_in[25];
  const float* b1    = (const float*)d_in[26];
  const float* W2    = (const float*)d_in[27];
  const float* b2    = (const float*)d_in[28];
  const float* Wf    = (const float*)d_in[29];
  const float* bf_   = (const float*)d_in[30];

  float* ws = (float*)d_ws;
  float* xb   = ws;            // x (B,H,L)
  float* skb  = ws + SZ;       // skip
  float* zbuf = ws + 2 * SZ;   // LN out -> later g buffer
  float* yb   = ws + 3 * SZ;   // gelu'd y (scan output) -> head relu out
  float* y2b  = ws + 4 * SZ;   // legacy bwd conv partial (unused on chunked path)
  float* tbb  = ws + 5 * SZ;   // (NB,B,H) = 24576 floats
  // chunked-scan extras (layout identical to round-6 proven-fit NEED)
  size_t off = 5 * SZ + 32768;                 // float offset, 16B-aligned
  float4* Pbuf = (float4*)(ws + off);          // 2*cH*cN float4 = 131072 floats
  float2* PWb  = (float2*)(ws + off + 131072); // cH*cN float2 = 32768 floats
  float2* Ebuf = (float2*)(ws + off + 131072 + 32768); // 2*cC*cB*cH*cN float2
  const size_t NEED = (off + 131072 + 32768 + (size_t)2 * cC * cB * cH * cN * 2) * 4;
  const bool chunked = ws_size >= NEED;

  dim3 ggrid(cL / 128, cH / 64, cB);
  dim3 sgrid(cC, cB * (cH / 32));

  temb_kernel<<<cB, 256, 0, stream>>>(t, W_t1, b_t1, W_t2, b_t2, Wt, bt_, tbb);
  init_kernel<<<(int)(SZ / 256), 256, 0, stream>>>(input, W_in, b_in, xb, skb);

  for (int i = 0; i < cNB; ++i) {
    pre_ln_kernel<<<cB * (cL / 64), 256, 0, stream>>>(xb, tbb, ln_g, ln_b, zbuf, i);
    if (chunked) {
      s4param_kernel<<<128, 256, 0, stream>>>(logdt, A_re, A_im, C_re, C_im, Pbuf, PWb, i);
      scanA1_kernel<<<sgrid, 256, 0, stream>>>(zbuf, Pbuf, Ebuf);
      scanB_kernel<<<2048, 256, 0, stream>>>(Ebuf, PWb);
      scanA2_kernel<<<sgrid, 256, 0, stream>>>(zbuf, Pbuf, Ebuf, Dp, yb, i);
    } else {
      scan_kernel<<<dim3(cB * (cH / 32), 2), 256, 0, stream>>>(zbuf, logdt, A_re, A_im, C_re, C_im, yb, y2b, i);
      gelu_kernel<<<(int)(SZ / 256), 256, 0, stream>>>(y2b, zbuf, Dp, yb, i);
    }
    gemm_act_kernel<<<ggrid, 256, 0, stream>>>(
        Wo_s4 + (size_t)i * cH * cH, bo_s4 + i * cH, yb, xb, tbb, feats, Wf, bf_, zbuf, i);
    gemm_dual_kernel<<<ggrid, 256, 0, stream>>>(
        W1 + (size_t)i * cH * cH, b1 + i * cH, W2 + (size_t)i * cH * cH, b2 + i * cH,
        zbuf, xb, skb);
  }

  // head: h = relu(skip^T Wh1 + bh1) stored (B,256,L) in yb, then scalar head
  gemm_relu_kernel<<<ggrid, 256, 0, stream>>>(Wh1, bh1, skb, yb);
  head_kernel<<<(cB * cL) / 256, 256, 0, stream>>>(yb, Wh2, bh2, input, (float*)d_out);
}

// Round 10
// 1843.757 us; speedup vs baseline: 1.5223x; 1.0479x over previous
//
#include <hip/hip_runtime.h>
#include <cmath>

constexpr int cB = 16, cL = 1024, cH = 256, cN = 64, cNB = 6, cNF = 4;
constexpr int cC = 8, cLc = cL / cC;           // chunked scan: 8 chunks of 128
constexpr size_t SZ = (size_t)cB * cH * cL;    // 4,194,304 elements per activation buffer

__device__ __forceinline__ float gelu_f(float v) {
  return 0.5f * v * (1.0f + erff(v * 0.70710678118654752f));
}

// ---------------------------------------------------------------- temb + tb
__global__ __launch_bounds__(256) void temb_kernel(
    const float* __restrict__ t, const float* __restrict__ Wt1, const float* __restrict__ bt1,
    const float* __restrict__ Wt2, const float* __restrict__ bt2,
    const float* __restrict__ Wt, const float* __restrict__ btb, float* __restrict__ tb) {
  __shared__ float e0[128], h1[256], h2[256];
  int b = blockIdx.x, tid = threadIdx.x;
  if (tid < 64) {
    float fr = expf((float)tid * (-logf(10000.0f) / 63.0f));
    float ang = t[b] * fr;
    e0[tid] = sinf(ang);
    e0[tid + 64] = cosf(ang);
  }
  __syncthreads();
  float a = bt1[tid];
  for (int k = 0; k < 128; ++k) a = fmaf(e0[k], Wt1[k * cH + tid], a);
  h1[tid] = a / (1.0f + expf(-a));   // silu
  __syncthreads();
  a = bt2[tid];
  for (int k = 0; k < 256; ++k) a = fmaf(h1[k], Wt2[k * cH + tid], a);
  h2[tid] = a / (1.0f + expf(-a));
  __syncthreads();
  for (int i = 0; i < cNB; ++i) {
    float acc = btb[i * cH + tid];
    const float* w = Wt + (size_t)i * cH * cH;
    for (int k = 0; k < 256; ++k) acc = fmaf(h2[k], w[k * cH + tid], acc);
    tb[((size_t)i * cB + b) * cH + tid] = acc;
  }
}

// ---------------------------------------------------------------- x init + skip=0
__global__ __launch_bounds__(256) void init_kernel(const float* __restrict__ inp,
    const float* __restrict__ Win, const float* __restrict__ bin,
    float* __restrict__ x, float* __restrict__ skip) {
  int idx = blockIdx.x * 256 + threadIdx.x;
  int l = idx & (cL - 1);
  int h = (idx >> 10) & (cH - 1);
  int b = idx >> 18;
  float v = fmaf(inp[b * cL + l], Win[h], bin[h]);
  x[idx] = v > 0.0f ? v : 0.0f;
  skip[idx] = 0.0f;
}

// ---------------------------------------------------------------- z = LN_H(x + tb)
__global__ __launch_bounds__(256) void pre_ln_kernel(const float* __restrict__ x,
    const float* __restrict__ tb_all, const float* __restrict__ ln_g, const float* __restrict__ ln_b,
    float* __restrict__ z, int blk) {
  __shared__ float red[8][64];
  __shared__ float mur[64], rsr[64];
  int b = blockIdx.x >> 4;
  int l0 = (blockIdx.x & 15) << 6;
  int lq = threadIdx.x & 63, hq = threadIdx.x >> 6; // 4 h-groups of 64
  int l = l0 + lq;
  const float* tb = tb_all + ((size_t)blk * cB + b) * cH;
  size_t base = ((size_t)b * cH + hq * 64) * cL + l;
  float s = 0.0f, s2 = 0.0f;
  for (int hh = 0; hh < 64; ++hh) {
    float v = x[base + (size_t)hh * cL] + tb[hq * 64 + hh];
    s += v;
    s2 = fmaf(v, v, s2);
  }
  red[hq][lq] = s;
  red[4 + hq][lq] = s2;
  __syncthreads();
  if (hq == 0) {
    float st = red[0][lq] + red[1][lq] + red[2][lq] + red[3][lq];
    float s2t = red[4][lq] + red[5][lq] + red[6][lq] + red[7][lq];
    float mu = st * (1.0f / cH);
    float var = s2t * (1.0f / cH) - mu * mu;
    mur[lq] = mu;
    rsr[lq] = rsqrtf(var + 1e-5f);
  }
  __syncthreads();
  float mu = mur[lq], r = rsr[lq];
  const float* g = ln_g + blk * cH;
  const float* be = ln_b + blk * cH;
  for (int hh = 0; hh < 64; ++hh) {
    int h = hq * 64 + hh;
    float v = (x[base + (size_t)hh * cL] + tb[h] - mu) * r;
    z[base + (size_t)hh * cL] = fmaf(v, g[h], be[h]);
  }
}

// ---------------------------------------------------------------- S4 per-block params
__global__ __launch_bounds__(256) void s4param_kernel(
    const float* __restrict__ logdt, const float* __restrict__ Are, const float* __restrict__ Aim,
    const float* __restrict__ Cre, const float* __restrict__ Cim,
    float4* __restrict__ P, float2* __restrict__ PW, int blk) {
  int idx = blockIdx.x * 256 + threadIdx.x;      // (dir*cH+h)*cN+n, 32768 total
  int n = idx & (cN - 1);
  int h = (idx >> 6) & (cH - 1);
  int dir = idx >> 14;
  float dt = expf(logdt[blk * cH + h]);
  float are = Are[((size_t)blk * cH + h) * cN + n];
  float aim = Aim[((size_t)blk * cH + h) * cN + n];
  float e = expf(-dt * are);
  float sn, cs;
  sincosf(dt * aim, &sn, &cs);
  float wr = e * cs, wi = e * sn;
  float inv = 1.0f / (are * are + aim * aim);
  float xr = wr - 1.0f, xi = wi;
  float tr = (xi * aim - xr * are) * inv;
  float ti = (-xr * aim - xi * are) * inv;
  float cr = Cre[(((size_t)blk * 2 + dir) * cH + h) * cN + n];
  float ci = Cim[(((size_t)blk * 2 + dir) * cH + h) * cN + n];
  float br = 2.0f * (cr * tr - ci * ti);
  float bi = 2.0f * (cr * ti + ci * tr);
  P[idx] = make_float4(wr, wi, br, bi);
  if (dir == 0) {
    float rr = wr, ri = wi;                      // w^128 by 7 squarings
#pragma unroll
    for (int q = 0; q < 7; ++q) {
      float nr = rr * rr - ri * ri;
      ri = 2.0f * rr * ri;
      rr = nr;
    }
    PW[h * cN + n] = make_float2(rr, ri);
  }
}

// ---------------------------------------------------------------- scan A1: per-chunk end states
// grid (cC, cB*cH/32, 2) — dir-parallel (round-6 proven config).
__global__ __launch_bounds__(256) void scanA1_kernel(const float* __restrict__ zb,
    const float4* __restrict__ P, float2* __restrict__ E) {
  int c = blockIdx.x, bh = blockIdx.y, dir = blockIdx.z;
  int b = bh >> 3, h0 = (bh & 7) << 5;
  int tid = threadIdx.x, wv = tid >> 6, lane = tid & 63;
  int hs = lane >> 3, j = lane & 7;
  int h = h0 + wv * 8 + hs;
  float wr[8], wi[8], sr[8] = {}, si[8] = {};
  const float4* Ph = P + ((size_t)dir * cH + h) * cN + j * 8;
#pragma unroll
  for (int k = 0; k < 8; ++k) { float4 p4 = Ph[k]; wr[k] = p4.x; wi[k] = p4.y; }
  const float* zr = zb + ((size_t)b * cH + h) * cL;
  int c0 = c * cLc;
  if (dir == 0) {
    for (int m = 0; m < cLc / 4; ++m) {
      float4 z4 = *(const float4*)&zr[c0 + (m << 2)];
#pragma unroll
      for (int q = 0; q < 4; ++q) {
        float zv = q == 0 ? z4.x : q == 1 ? z4.y : q == 2 ? z4.z : z4.w;
#pragma unroll
        for (int k = 0; k < 8; ++k) {
          float nr = fmaf(wr[k], sr[k], zv);
          nr = fmaf(-wi[k], si[k], nr);
          float ni = wr[k] * si[k];
          ni = fmaf(wi[k], sr[k], ni);
          sr[k] = nr; si[k] = ni;
        }
      }
    }
  } else {
    for (int m = cLc / 4 - 1; m >= 0; --m) {
      float4 z4 = *(const float4*)&zr[c0 + (m << 2)];
#pragma unroll
      for (int q = 3; q >= 0; --q) {
        float zv = q == 0 ? z4.x : q == 1 ? z4.y : q == 2 ? z4.z : z4.w;
#pragma unroll
        for (int k = 0; k < 8; ++k) {
          float nr = fmaf(wr[k], sr[k], zv);
          nr = fmaf(-wi[k], si[k], nr);
          float ni = wr[k] * si[k];
          ni = fmaf(wi[k], sr[k], ni);
          sr[k] = nr; si[k] = ni;
        }
      }
    }
  }
  float2* Eo = E + ((((size_t)dir * cC + c) * cB + b) * cH + h) * cN + j * 8;
#pragma unroll
  for (int k = 0; k < 8; ++k) Eo[k] = make_float2(sr[k], si[k]);
}

// ---------------------------------------------------------------- scan B: transform E in-place into per-chunk carries.
__global__ __launch_bounds__(256) void scanB_kernel(float2* __restrict__ E,
    const float2* __restrict__ PW) {
  int idx = blockIdx.x * 256 + threadIdx.x;  // ((dir*cB+b)*cH+h)*cN+n, 524288 total
  int n = idx & (cN - 1);
  int h = (idx >> 6) & (cH - 1);
  int b = (idx >> 14) & (cB - 1);
  int dir = idx >> 18;
  float2 q2 = PW[h * cN + n];
  float qr = q2.x, qi = q2.y;
  const size_t cs = (size_t)cB * cH * cN;
  size_t e0 = ((((size_t)dir * cC) * cB + b) * cH + h) * cN + n;
  float sr = 0.0f, si = 0.0f;
  if (dir == 0) {
    for (int cc = 0; cc < cC; ++cc) {
      float2 e = E[e0 + cc * cs];
      E[e0 + cc * cs] = make_float2(sr, si);
      float nr = fmaf(qr, sr, e.x); nr = fmaf(-qi, si, nr);
      float ni = fmaf(qr, si, e.y); ni = fmaf(qi, sr, ni);
      sr = nr; si = ni;
    }
  } else {
    for (int cc = cC - 1; cc >= 0; --cc) {
      float2 e = E[e0 + cc * cs];
      E[e0 + cc * cs] = make_float2(sr, si);
      float nr = fmaf(qr, sr, e.x); nr = fmaf(-qi, si, nr);
      float ni = fmaf(qr, si, e.y); ni = fmaf(qi, sr, ni);
      sr = nr; si = ni;
    }
  }
}

// ---------------------------------------------------------------- scan A2: 512 threads, dirs CONCURRENT
// waves 0-3: fwd -> accF; waves 4-7: bwd -> accB; barrier; combine = gelu(accF+accB+z*D).
__global__ __launch_bounds__(512) void scanA2_kernel(const float* __restrict__ zb,
    const float4* __restrict__ P, const float2* __restrict__ E, const float* __restrict__ Dpb,
    float* __restrict__ y) {
  __shared__ float accF[32][cLc + 1];
  __shared__ float accB[32][cLc + 1];
  int c = blockIdx.x, bh = blockIdx.y;
  int b = bh >> 3, h0 = (bh & 7) << 5;
  int tid = threadIdx.x;
  int wave = tid >> 6;
  int dir = wave >> 2;                 // waves 0-3 fwd, 4-7 bwd
  int wv = wave & 3, lane = tid & 63;
  int hs = lane >> 3, j = lane & 7;
  int lch = wv * 8 + hs;               // 0..31 channel within tile (per dir-group)
  int h = h0 + lch;
  const float* zr = zb + ((size_t)b * cH + h) * cL;
  int c0 = c * cLc;
  float wr[8], wi[8], br[8], bi[8], sr[8], si[8];
  const float4* Ph = P + ((size_t)dir * cH + h) * cN + j * 8;
  const float2* Cc = E + ((((size_t)dir * cC + c) * cB + b) * cH + h) * cN + j * 8;
#pragma unroll
  for (int k = 0; k < 8; ++k) {
    float4 p4 = Ph[k];
    wr[k] = p4.x; wi[k] = p4.y; br[k] = p4.z; bi[k] = p4.w;
    float2 e2 = Cc[k];
    sr[k] = e2.x; si[k] = e2.y;
  }
  if (dir == 0) {
    for (int m = 0; m < cLc / 4; ++m) {
      float4 z4 = *(const float4*)&zr[c0 + (m << 2)];
#pragma unroll
      for (int q = 0; q < 4; ++q) {
        float zv = q == 0 ? z4.x : q == 1 ? z4.y : q == 2 ? z4.z : z4.w;
        float p = 0.0f;
#pragma unroll
        for (int k = 0; k < 8; ++k) {
          float nr = fmaf(wr[k], sr[k], zv);
          nr = fmaf(-wi[k], si[k], nr);
          float ni = wr[k] * si[k];
          ni = fmaf(wi[k], sr[k], ni);
          sr[k] = nr; si[k] = ni;
          p = fmaf(br[k], nr, p);
          p = fmaf(-bi[k], ni, p);
        }
        p += __shfl_xor(p, 1);
        p += __shfl_xor(p, 2);
        p += __shfl_xor(p, 4);
        if (j == 0) accF[lch][(m << 2) + q] = p;
      }
    }
  } else {
    for (int m = cLc / 4 - 1; m >= 0; --m) {
      float4 z4 = *(const float4*)&zr[c0 + (m << 2)];
#pragma unroll
      for (int q = 3; q >= 0; --q) {
        float zv = q == 0 ? z4.x : q == 1 ? z4.y : q == 2 ? z4.z : z4.w;
        float p = 0.0f;
#pragma unroll
        for (int k = 0; k < 8; ++k) {
          p = fmaf(br[k], sr[k], p);
          p = fmaf(-bi[k], si[k], p);
        }
        p += __shfl_xor(p, 1);
        p += __shfl_xor(p, 2);
        p += __shfl_xor(p, 4);
        if (j == 0) accB[lch][(m << 2) + q] = p;
#pragma unroll
        for (int k = 0; k < 8; ++k) {
          float nr = fmaf(wr[k], sr[k], zv);
          nr = fmaf(-wi[k], si[k], nr);
          float ni = wr[k] * si[k];
          ni = fmaf(wi[k], sr[k], ni);
          sr[k] = nr; si[k] = ni;
        }
      }
    }
  }
  __syncthreads();
  // ---- combine over 512 threads: each handles 8 floats of one channel row
  int lc2 = tid >> 4, part = tid & 15;
  int hh = h0 + lc2;
  float Dv = Dpb[hh];
  const float* zrow = zb + ((size_t)b * cH + hh) * cL + c0;
  float* yrow = y + ((size_t)b * cH + hh) * cL + c0;
#pragma unroll
  for (int g = 0; g < 2; ++g) {
    int l = part * 8 + g * 4;
    float4 z4 = *(const float4*)&zrow[l];
    float4 o;
    o.x = gelu_f(accF[lc2][l + 0] + accB[lc2][l + 0] + z4.x * Dv);
    o.y = gelu_f(accF[lc2][l + 1] + accB[lc2][l + 1] + z4.y * Dv);
    o.z = gelu_f(accF[lc2][l + 2] + accB[lc2][l + 2] + z4.z * Dv);
    o.w = gelu_f(accF[lc2][l + 3] + accB[lc2][l + 3] + z4.w * Dv);
    *(float4*)&yrow[l] = o;
  }
}

// ---------------------------------------------------------------- LEGACY single-pass scan (ws fallback)
__global__ __launch_bounds__(256) void scan_kernel(
    const float* __restrict__ zb, const float* __restrict__ log_dt,
    const float* __restrict__ A_re, const float* __restrict__ A_im,
    const float* __restrict__ C_re, const float* __restrict__ C_im,
    float* __restrict__ yf, float* __restrict__ ybk, int blk) {
  int dir = blockIdx.y;
  int b = blockIdx.x >> 3;
  int h0 = (blockIdx.x & 7) << 5;
  int tid = threadIdx.x;
  int wv = tid >> 6, lane = tid & 63;
  int hs = lane >> 3, j = lane & 7;
  int h = h0 + wv * 8 + hs;
  float dt = expf(log_dt[blk * cH + h]);
  const float* Ar = A_re + ((size_t)blk * cH + h) * cN;
  const float* Ai = A_im + ((size_t)blk * cH + h) * cN;
  const float* Cr = C_re + (((size_t)blk * 2 + dir) * cH + h) * cN;
  const float* Ci = C_im + (((size_t)blk * 2 + dir) * cH + h) * cN;
  float wr[8], wi[8], br[8], bi[8], sr[8], si[8];
#pragma unroll
  for (int k = 0; k < 8; ++k) {
    int n = j * 8 + k;
    float are = Ar[n], aim = Ai[n];
    float e = expf(-dt * are);
    float sn, cs;
    sincosf(dt * aim, &sn, &cs);
    float w_r = e * cs, w_i = e * sn;
    float inv = 1.0f / (are * are + aim * aim);
    float xr = w_r - 1.0f, xi = w_i;
    float tr = (xi * aim - xr * are) * inv;
    float ti = (-xr * aim - xi * are) * inv;
    float cr = Cr[n], ci = Ci[n];
    br[k] = 2.0f * (cr * tr - ci * ti);
    bi[k] = 2.0f * (cr * ti + ci * tr);
    wr[k] = w_r; wi[k] = w_i;
    sr[k] = 0.0f; si[k] = 0.0f;
  }
  const float* zr = zb + ((size_t)b * cH + h) * cL;
  if (dir == 0) {
    float* yr = yf + ((size_t)b * cH + h) * cL;
    for (int l = 0; l < cL; ++l) {
      float zv = zr[l];
      float p = 0.0f;
#pragma unroll
      for (int k = 0; k < 8; ++k) {
        float nr = fmaf(wr[k], sr[k], zv);
        nr = fmaf(-wi[k], si[k], nr);
        float ni = wr[k] * si[k];
        ni = fmaf(wi[k], sr[k], ni);
        sr[k] = nr; si[k] = ni;
        p = fmaf(br[k], nr, p);
        p = fmaf(-bi[k], ni, p);
      }
      p += __shfl_xor(p, 1);
      p += __shfl_xor(p, 2);
      p += __shfl_xor(p, 4);
      if (j == 0) yr[l] = p;
    }
  } else {
    float* yr = ybk + ((size_t)b * cH + h) * cL;
    for (int l = cL - 1; l >= 0; --l) {
      float p = 0.0f;
#pragma unroll
      for (int k = 0; k < 8; ++k) {
        p = fmaf(br[k], sr[k], p);
        p = fmaf(-bi[k], si[k], p);
      }
      p += __shfl_xor(p, 1);
      p += __shfl_xor(p, 2);
      p += __shfl_xor(p, 4);
      if (j == 0) yr[l] = p;
      float zv = zr[l];
#pragma unroll
      for (int k = 0; k < 8; ++k) {
        float nr = fmaf(wr[k], sr[k], zv);
        nr = fmaf(-wi[k], si[k], nr);
        float ni = wr[k] * si[k];
        ni = fmaf(wi[k], sr[k], ni);
        sr[k] = nr; si[k] = ni;
      }
    }
  }
}

// ---------------------------------------------------------------- y = gelu(yf + yb + z*D)  (legacy path only)
__global__ __launch_bounds__(256) void gelu_kernel(const float* __restrict__ y2,
    const float* __restrict__ zz, const float* __restrict__ Dp, float* __restrict__ y1io, int blk) {
  int idx = blockIdx.x * 256 + threadIdx.x;
  int h = (idx >> 10) & (cH - 1);
  float v = y1io[idx] + y2[idx] + zz[idx] * Dp[blk * cH + h];
  y1io[idx] = gelu_f(v);
}

// ================================================================ GEMM core: 128(l) x 64(o) tile,
// 256 threads, 8x4 micro-tile. acc[o_i 0..3][l_i 0..7].
#define GEMM_CORE(WPTR)                                                          \
  int l0 = blockIdx.x * 128, o0 = blockIdx.y * 64, b = blockIdx.z;               \
  int tid = threadIdx.x;                                                         \
  int tx = tid & 15, ty = tid >> 4;                                              \
  const float* Gb = G + (size_t)b * cH * cL;                                     \
  float acc[4][8] = {};                                                          \
  {                                                                              \
    int ar = tid >> 6, ac = tid & 63;                                            \
    int brr = tid >> 7, bc = tid & 127;                                          \
    for (int kk = 0; kk < cH; kk += 16) {                                        \
      _Pragma("unroll")                                                          \
      for (int rr = 0; rr < 4; ++rr)                                             \
        As[ar + rr * 4][ac] = (WPTR)[(size_t)(kk + ar + rr * 4) * cH + o0 + ac]; \
      _Pragma("unroll")                                                          \
      for (int rr = 0; rr < 8; ++rr)                                             \
        Bs[brr + rr * 2][bc] = Gb[(size_t)(kk + brr + rr * 2) * cL + l0 + bc];   \
      __syncthreads();                                                           \
      _Pragma("unroll")                                                          \
      for (int k = 0; k < 16; ++k) {                                             \
        const float4 av = *(const float4*)&As[k][ty << 2];                       \
        const float4 b0 = *(const float4*)&Bs[k][tx << 3];                       \
        const float4 b1 = *(const float4*)&Bs[k][(tx << 3) + 4];                 \
        FMA8(0, av.x) FMA8(1, av.y) FMA8(2, av.z) FMA8(3, av.w)                  \
      }                                                                          \
      __syncthreads();                                                           \
    }                                                                            \
  }

#define FMA8(oi, aw)                                     \
  acc[oi][0] = fmaf(aw, b0.x, acc[oi][0]);               \
  acc[oi][1] = fmaf(aw, b0.y, acc[oi][1]);               \
  acc[oi][2] = fmaf(aw, b0.z, acc[oi][2]);               \
  acc[oi][3] = fmaf(aw, b0.w, acc[oi][3]);               \
  acc[oi][4] = fmaf(aw, b1.x, acc[oi][4]);               \
  acc[oi][5] = fmaf(aw, b1.y, acc[oi][5]);               \
  acc[oi][6] = fmaf(aw, b1.z, acc[oi][6]);               \
  acc[oi][7] = fmaf(aw, b1.w, acc[oi][7]);

// ---------------------------------------------------------------- s4-out GEMM fused with gated activation
__global__ __launch_bounds__(256) void gemm_act_kernel(const float* __restrict__ W,
    const float* __restrict__ bo, const float* __restrict__ G,
    const float* __restrict__ x, const float* __restrict__ tb_all,
    const float* __restrict__ features, const float* __restrict__ Wf,
    const float* __restrict__ bfb, float* __restrict__ C, int blk) {
  __shared__ float As[16][64];
  __shared__ float Bs[16][128];
  GEMM_CORE(W)
  int lbase = l0 + (tx << 3);
  float4 fv[8];
#pragma unroll
  for (int li = 0; li < 8; ++li)
    fv[li] = *(const float4*)&features[((size_t)b * cL + lbase + li) * cNF];
  const float* Wfi = Wf + (size_t)blk * cNF * cH;
  const float* tb = tb_all + ((size_t)blk * cB + b) * cH;
#pragma unroll
  for (int oi = 0; oi < 4; ++oi) {
    int oo = o0 + (ty << 2) + oi;
    float wf0 = Wfi[oo], wf1 = Wfi[cH + oo], wf2 = Wfi[2 * cH + oo], wf3 = Wfi[3 * cH + oo];
    float bb = bo[oo] + bfb[blk * cH + oo] + tb[oo];
    size_t row = ((size_t)b * cH + oo) * cL + lbase;
    const float4 x0 = *(const float4*)&x[row];
    const float4 x1 = *(const float4*)&x[row + 4];
    float xv[8] = {x0.x, x0.y, x0.z, x0.w, x1.x, x1.y, x1.z, x1.w};
    float out[8];
#pragma unroll
    for (int li = 0; li < 8; ++li) {
      float v = acc[oi][li] + bb + xv[li];
      v = fmaf(fv[li].x, wf0, v);
      v = fmaf(fv[li].y, wf1, v);
      v = fmaf(fv[li].z, wf2, v);
      v = fmaf(fv[li].w, wf3, v);
      float tv = tanhf(v);
      float sv = 1.0f / (1.0f + expf(-v));
      out[li] = tv * sv;
    }
    *(float4*)&C[row] = make_float4(out[0], out[1], out[2], out[3]);
    *(float4*)&C[row + 4] = make_float4(out[4], out[5], out[6], out[7]);
  }
}

// ---------------------------------------------------------------- dual GEMM: x += g@W1 + b1 ; skip += g@W2 + b2
__global__ __launch_bounds__(256) void gemm_dual_kernel(const float* __restrict__ W1,
    const float* __restrict__ b1, const float* __restrict__ W2, const float* __restrict__ b2,
    const float* __restrict__ G, float* __restrict__ xio, float* __restrict__ skio) {
  __shared__ float As[16][64];
  __shared__ float As2[16][64];
  __shared__ float Bs[16][128];
  int l0 = blockIdx.x * 128, o0 = blockIdx.y * 64, b = blockIdx.z;
  int tid = threadIdx.x;
  int tx = tid & 15, ty = tid >> 4;
  const float* Gb = G + (size_t)b * cH * cL;
  float acc[4][8] = {};
  float acc2[4][8] = {};
  {
    int ar = tid >> 6, ac = tid & 63;
    int brr = tid >> 7, bc = tid & 127;
    for (int kk = 0; kk < cH; kk += 16) {
#pragma unroll
      for (int rr = 0; rr < 4; ++rr) {
        As[ar + rr * 4][ac] = W1[(size_t)(kk + ar + rr * 4) * cH + o0 + ac];
        As2[ar + rr * 4][ac] = W2[(size_t)(kk + ar + rr * 4) * cH + o0 + ac];
      }
#pragma unroll
      for (int rr = 0; rr < 8; ++rr)
        Bs[brr + rr * 2][bc] = Gb[(size_t)(kk + brr + rr * 2) * cL + l0 + bc];
      __syncthreads();
#pragma unroll
      for (int k = 0; k < 16; ++k) {
        const float4 b0 = *(const float4*)&Bs[k][tx << 3];
        const float4 b1v = *(const float4*)&Bs[k][(tx << 3) + 4];
        {
          const float4 av = *(const float4*)&As[k][ty << 2];
#define FMA8D(AC, oi, aw)                          \
  AC[oi][0] = fmaf(aw, b0.x, AC[oi][0]);           \
  AC[oi][1] = fmaf(aw, b0.y, AC[oi][1]);           \
  AC[oi][2] = fmaf(aw, b0.z, AC[oi][2]);           \
  AC[oi][3] = fmaf(aw, b0.w, AC[oi][3]);           \
  AC[oi][4] = fmaf(aw, b1v.x, AC[oi][4]);          \
  AC[oi][5] = fmaf(aw, b1v.y, AC[oi][5]);          \
  AC[oi][6] = fmaf(aw, b1v.z, AC[oi][6]);          \
  AC[oi][7] = fmaf(aw, b1v.w, AC[oi][7]);
          FMA8D(acc, 0, av.x) FMA8D(acc, 1, av.y) FMA8D(acc, 2, av.z) FMA8D(acc, 3, av.w)
        }
        {
          const float4 av = *(const float4*)&As2[k][ty << 2];
          FMA8D(acc2, 0, av.x) FMA8D(acc2, 1, av.y) FMA8D(acc2, 2, av.z) FMA8D(acc2, 3, av.w)
        }
      }
      __syncthreads();
    }
  }
  int lbase = l0 + (tx << 3);
#pragma unroll
  for (int oi = 0; oi < 4; ++oi) {
    int oo = o0 + (ty << 2) + oi;
    float bb1 = b1[oo], bb2 = b2[oo];
    size_t row = ((size_t)b * cH + oo) * cL + lbase;
    float4 xv0 = *(const float4*)&xio[row];
    float4 xv1 = *(const float4*)&xio[row + 4];
    float4 sv0 = *(const float4*)&skio[row];
    float4 sv1 = *(const float4*)&skio[row + 4];
    xv0.x += acc[oi][0] + bb1; xv0.y += acc[oi][1] + bb1;
    xv0.z += acc[oi][2] + bb1; xv0.w += acc[oi][3] + bb1;
    xv1.x += acc[oi][4] + bb1; xv1.y += acc[oi][5] + bb1;
    xv1.z += acc[oi][6] + bb1; xv1.w += acc[oi][7] + bb1;
    sv0.x += acc2[oi][0] + bb2; sv0.y += acc2[oi][1] + bb2;
    sv0.z += acc2[oi][2] + bb2; sv0.w += acc2[oi][3] + bb2;
    sv1.x += acc2[oi][4] + bb2; sv1.y += acc2[oi][5] + bb2;
    sv1.z += acc2[oi][6] + bb2; sv1.w += acc2[oi][7] + bb2;
    *(float4*)&xio[row] = xv0;
    *(float4*)&xio[row + 4] = xv1;
    *(float4*)&skio[row] = sv0;
    *(float4*)&skio[row + 4] = sv1;
  }
}

// ---------------------------------------------------------------- head GEMM: C = relu(skip^T Wh1 + bh1), (B,256,L)
__global__ __launch_bounds__(256) void gemm_relu_kernel(const float* __restrict__ W,
    const float* __restrict__ bias, const float* __restrict__ G, float* __restrict__ C) {
  __shared__ float As[16][64];
  __shared__ float Bs[16][128];
  GEMM_CORE(W)
  int lbase = l0 + (tx << 3);
#pragma unroll
  for (int oi = 0; oi < 4; ++oi) {
    int oo = o0 + (ty << 2) + oi;
    float bb = bias[oo];
    size_t row = ((size_t)b * cH + oo) * cL + lbase;
    float4 v0, v1;
    v0.x = fmaxf(acc[oi][0] + bb, 0.0f); v0.y = fmaxf(acc[oi][1] + bb, 0.0f);
    v0.z = fmaxf(acc[oi][2] + bb, 0.0f); v0.w = fmaxf(acc[oi][3] + bb, 0.0f);
    v1.x = fmaxf(acc[oi][4] + bb, 0.0f); v1.y = fmaxf(acc[oi][5] + bb, 0.0f);
    v1.z = fmaxf(acc[oi][6] + bb, 0.0f); v1.w = fmaxf(acc[oi][7] + bb, 0.0f);
    *(float4*)&C[row] = v0;
    *(float4*)&C[row + 4] = v1;
  }
}

// ---------------------------------------------------------------- out = h @ Wh2 + bh2 + input
__global__ __launch_bounds__(256) void head_kernel(const float* __restrict__ hb,
    const float* __restrict__ Wh2, const float* __restrict__ bh2,
    const float* __restrict__ inp, float* __restrict__ out) {
  int idx = blockIdx.x * 256 + threadIdx.x; // B*L
  int b = idx >> 10, l = idx & (cL - 1);
  float acc = bh2[0] + inp[idx];
  const float* hr = hb + (size_t)b * cH * cL + l;
  for (int o = 0; o < cH; ++o) acc = fmaf(hr[(size_t)o * cL], Wh2[o], acc);
  out[idx] = acc;
}

// ----------------------------------------------------------------
extern "C" void kernel_launch(void* const* d_in, const int* in_sizes, int n_in,
                              void* d_out, int out_size, void* d_ws, size_t ws_size,
                              hipStream_t stream) {
  const float* input = (const float*)d_in[0];
  const float* t     = (const float*)d_in[1];
  const float* feats = (const float*)d_in[2];
  const float* W_in  = (const float*)d_in[3];
  const float* b_in  = (const float*)d_in[4];
  const float* W_t1  = (const float*)d_in[5];
  const float* b_t1  = (const float*)d_in[6];
  const float* W_t2  = (const float*)d_in[7];
  const float* b_t2  = (const float*)d_in[8];
  const float* Wh1   = (const float*)d_in[9];
  const float* bh1   = (const float*)d_in[10];
  const float* Wh2   = (const float*)d_in[11];
  const float* bh2   = (const float*)d_in[12];
  const float* ln_g  = (const float*)d_in[13];
  const float* ln_b  = (const float*)d_in[14];
  const float* logdt = (const float*)d_in[15];
  const float* A_re  = (const float*)d_in[16];
  const float* A_im  = (const float*)d_in[17];
  const float* C_re  = (const float*)d_in[18];
  const float* C_im  = (const float*)d_in[19];
  const float* Dp    = (const float*)d_in[20];
  const float* Wo_s4 = (const float*)d_in[21];
  const float* bo_s4 = (const float*)d_in[22];
  const float* Wt    = (const float*)d_in[23];
  const float* bt_   = (const float*)d_in[24];
  const float* W1    = (const float*)d_in[25];
  const float* b1    = (const float*)d_in[26];
  const float* W2    = (const float*)d_in[27];
  const float* b2    = (const float*)d_in[28];
  const float* Wf    = (const float*)d_in[29];
  const float* bf_   = (const float*)d_in[30];

  float* ws = (float*)d_ws;
  float* xb   = ws;            // x (B,H,L)
  float* skb  = ws + SZ;       // skip
  float* zbuf = ws + 2 * SZ;   // LN out -> later g buffer
  float* yb   = ws + 3 * SZ;   // gelu'd y (scan output) -> head relu out
  float* y2b  = ws + 4 * SZ;   // legacy bwd conv partial (unused on chunked path)
  float* tbb  = ws + 5 * SZ;   // (NB,B,H) = 24576 floats
  // chunked-scan extras (layout identical to round-6/8 proven-fit NEED)
  size_t off = 5 * SZ + 32768;                 // float offset, 16B-aligned
  float4* Pbuf = (float4*)(ws + off);          // 2*cH*cN float4 = 131072 floats
  float2* PWb  = (float2*)(ws + off + 131072); // cH*cN float2 = 32768 floats
  float2* Ebuf = (float2*)(ws + off + 131072 + 32768); // 2*cC*cB*cH*cN float2
  const size_t NEED = (off + 131072 + 32768 + (size_t)2 * cC * cB * cH * cN * 2) * 4;
  const bool chunked = ws_size >= NEED;

  dim3 ggrid(cL / 128, cH / 64, cB);
  dim3 sgridA1(cC, cB * (cH / 32), 2);
  dim3 sgridA2(cC, cB * (cH / 32));

  temb_kernel<<<cB, 256, 0, stream>>>(t, W_t1, b_t1, W_t2, b_t2, Wt, bt_, tbb);
  init_kernel<<<(int)(SZ / 256), 256, 0, stream>>>(input, W_in, b_in, xb, skb);

  for (int i = 0; i < cNB; ++i) {
    pre_ln_kernel<<<cB * (cL / 64), 256, 0, stream>>>(xb, tbb, ln_g, ln_b, zbuf, i);
    if (chunked) {
      s4param_kernel<<<128, 256, 0, stream>>>(logdt, A_re, A_im, C_re, C_im, Pbuf, PWb, i);
      scanA1_kernel<<<sgridA1, 256, 0, stream>>>(zbuf, Pbuf, Ebuf);
      scanB_kernel<<<2048, 256, 0, stream>>>(Ebuf, PWb);
      scanA2_kernel<<<sgridA2, 512, 0, stream>>>(zbuf, Pbuf, Ebuf, Dp + (size_t)i * cH, yb);
    } else {
      scan_kernel<<<dim3(cB * (cH / 32), 2), 256, 0, stream>>>(zbuf, logdt, A_re, A_im, C_re, C_im, yb, y2b, i);
      gelu_kernel<<<(int)(SZ / 256), 256, 0, stream>>>(y2b, zbuf, Dp, yb, i);
    }
    gemm_act_kernel<<<ggrid, 256, 0, stream>>>(
        Wo_s4 + (size_t)i * cH * cH, bo_s4 + i * cH, yb, xb, tbb, feats, Wf, bf_, zbuf, i);
    gemm_dual_kernel<<<ggrid, 256, 0, stream>>>(
        W1 + (size_t)i * cH * cH, b1 + i * cH, W2 + (size_t)i * cH * cH, b2 + i * cH,
        zbuf, xb, skb);
  }

  // head: h = relu(skip^T Wh1 + bh1) stored (B,256,L) in yb, then scalar head
  gemm_relu_kernel<<<ggrid, 256, 0, stream>>>(Wh1, bh1, skb, yb);
  head_kernel<<<(cB * cL) / 256, 256, 0, stream>>>(yb, Wh2, bh2, input, (float*)d_out);
}